// Round 5
// baseline (784.583 us; speedup 1.0000x reference)
//
#include <hip/hip_runtime.h>
#include <hip/hip_bf16.h>

// NeuronGAT forward. Round 4:
//  - attn: NCHUNK 16->32 (512->1024 blocks, 2->4 blocks/CU). pacc/pl overlay
//    the dead res..h1 / h2 regions exactly (no extra workspace).
//  - all GEMMs through gemm64 (4x4 microtile); skinny kernel removed
//    (its 1-scalar-per-4-FMA LDS pattern was LDS-bound).

#define NEG 0.2f

__device__ __forceinline__ float leaky(float v) { return v > 0.f ? v : NEG * v; }

// ---------------------------------------------------------------- GEMM 64x64
// C[M,N] = act(A[M,K] @ B[K,N] + bias). M%64==0, K%32==0, N arbitrary (<=64*grid.x).
__global__ __launch_bounds__(256) void gemm64(
    const float* __restrict__ A, const float* __restrict__ B,
    const float* __restrict__ bias, float* __restrict__ C,
    int M, int N, int K, int act)
{
    __shared__ __align__(16) float As[32][64];
    __shared__ __align__(16) float Bs[32][64];
    const int tx = threadIdx.x & 15, ty = threadIdx.x >> 4;
    const int row0 = blockIdx.y * 64, col0 = blockIdx.x * 64;
    const int ar = threadIdx.x & 63, akq = threadIdx.x >> 6; // A stage
    const int bc = threadIdx.x & 15, bk = threadIdx.x >> 4;  // B stage
    float acc[4][4] = {};
    for (int k0 = 0; k0 < K; k0 += 32) {
        { // A: 64 rows x 32 k, thread reads 8 contiguous k, writes transposed
            const float* ap = A + (size_t)(row0 + ar) * K + k0 + akq * 8;
            float4 a0 = *(const float4*)ap;
            float4 a1 = *(const float4*)(ap + 4);
            int kb = akq * 8;
            As[kb + 0][ar] = a0.x; As[kb + 1][ar] = a0.y;
            As[kb + 2][ar] = a0.z; As[kb + 3][ar] = a0.w;
            As[kb + 4][ar] = a1.x; As[kb + 5][ar] = a1.y;
            As[kb + 6][ar] = a1.z; As[kb + 7][ar] = a1.w;
        }
#pragma unroll
        for (int j = 0; j < 2; ++j) { // B: 32 k x 64 cols
            int kk = bk + j * 16;
            int col = col0 + bc * 4;
            float4 b;
            if (col + 3 < N) {
                b = *(const float4*)&B[(size_t)(k0 + kk) * N + col];
            } else {
                b.x = col < N ? B[(size_t)(k0 + kk) * N + col] : 0.f;
                b.y = col + 1 < N ? B[(size_t)(k0 + kk) * N + col + 1] : 0.f;
                b.z = col + 2 < N ? B[(size_t)(k0 + kk) * N + col + 2] : 0.f;
                b.w = col + 3 < N ? B[(size_t)(k0 + kk) * N + col + 3] : 0.f;
            }
            *(float4*)&Bs[kk][bc * 4] = b;
        }
        __syncthreads();
#pragma unroll
        for (int kk = 0; kk < 32; ++kk) {
            float4 a4 = *(const float4*)&As[kk][ty * 4];
            float4 b4 = *(const float4*)&Bs[kk][tx * 4];
            float a[4] = {a4.x, a4.y, a4.z, a4.w};
            float b[4] = {b4.x, b4.y, b4.z, b4.w};
#pragma unroll
            for (int i = 0; i < 4; ++i)
#pragma unroll
                for (int j = 0; j < 4; ++j) acc[i][j] += a[i] * b[j];
        }
        __syncthreads();
    }
#pragma unroll
    for (int i = 0; i < 4; ++i) {
        int r = row0 + ty * 4 + i;
#pragma unroll
        for (int j = 0; j < 4; ++j) {
            int c = col0 + tx * 4 + j;
            if (c < N) {
                float v = acc[i][j] + (bias ? bias[c] : 0.f);
                if (act) v = leaky(v);
                C[(size_t)r * N + c] = v;
            }
        }
    }
}

// ------------------------------------------------- GAT attention scores
__global__ void sd_kernel(const float* __restrict__ hw, const float* __restrict__ a_s,
                          const float* __restrict__ a_d, float* __restrict__ sval,
                          float* __restrict__ dval, int Nn, int H)
{
    int i = blockIdx.x * blockDim.x + threadIdx.x;
    if (i >= Nn * H) return;
    int n = i / H, h = i - n * H;
    const float4* row = (const float4*)(hw + (size_t)n * H * 64 + h * 64);
    const float4* as4 = (const float4*)(a_s + h * 64);
    const float4* ad4 = (const float4*)(a_d + h * 64);
    float s = 0.f, d = 0.f;
#pragma unroll
    for (int c = 0; c < 16; ++c) {
        float4 x = row[c], a = as4[c], b = ad4[c];
        s += x.x * a.x + x.y * a.y + x.z * a.z + x.w * a.w;
        d += x.x * b.x + x.y * b.y + x.z * b.z + x.w * b.w;
    }
    sval[i] = s;
    dval[i] = d;
}

// ------------------------------------------------- CSR build (by dst)
__global__ void csr_count(const int* __restrict__ ei, int* __restrict__ cnt, int E) {
    int i = blockIdx.x * 256 + threadIdx.x;
    if (i < E) atomicAdd(&cnt[ei[E + i]], 1);
}

__global__ __launch_bounds__(256) void csr_scan(const int* __restrict__ cnt,
                                                int* __restrict__ rowptr,
                                                int* __restrict__ fill, int Nn)
{
    __shared__ int part[256];
    int t = threadIdx.x;
    int loc[32];
    int s = 0;
#pragma unroll
    for (int j = 0; j < 32; ++j) { loc[j] = s; s += cnt[t * 32 + j]; }
    part[t] = s;
    __syncthreads();
    for (int d = 1; d < 256; d <<= 1) {
        int v = (t >= d) ? part[t - d] : 0;
        __syncthreads();
        part[t] += v;
        __syncthreads();
    }
    int off = (t > 0) ? part[t - 1] : 0;
#pragma unroll
    for (int j = 0; j < 32; ++j) {
        int v = off + loc[j];
        rowptr[t * 32 + j] = v;
        fill[t * 32 + j] = v;
    }
    if (t == 255) rowptr[Nn] = part[255];
}

__global__ void csr_scatter(const int* __restrict__ ei, int* __restrict__ fill,
                            int* __restrict__ srcidx, int E) {
    int i = blockIdx.x * 256 + threadIdx.x;
    if (i < E) {
        int d = ei[E + i];
        int p = atomicAdd(&fill[d], 1);
        srcidx[p] = ei[i];
    }
}

// ------------------------------------------------- fused GAT gather
template <int H>
__global__ __launch_bounds__(256) void gat_gather(
    const int* __restrict__ rowptr, const int* __restrict__ srcidx,
    const float* __restrict__ hw, const float* __restrict__ sval,
    const float* __restrict__ dval, float* __restrict__ gout, int Nn)
{
    const int node = blockIdx.x * 4 + (threadIdx.x >> 6);
    const int lane = threadIdx.x & 63;
    const int beg = rowptr[node], end = rowptr[node + 1];
    const int C = H * 64;
    float dv[H], es[H], mh[H], lh[H], inv[H], acc[H];
#pragma unroll
    for (int h = 0; h < H; ++h) {
        dv[h] = dval[node * H + h];
        es[h] = leaky(sval[node * H + h] + dv[h]); // self-loop score
        mh[h] = -1e30f;
        lh[h] = 0.f;
    }
    for (int i = beg + lane; i < end; i += 64) {
        int s = srcidx[i];
#pragma unroll
        for (int h = 0; h < H; ++h)
            mh[h] = fmaxf(mh[h], leaky(sval[s * H + h] + dv[h]));
    }
#pragma unroll
    for (int h = 0; h < H; ++h) {
        float m = mh[h];
        for (int off = 32; off; off >>= 1) m = fmaxf(m, __shfl_xor(m, off));
        mh[h] = fmaxf(m, es[h]);
    }
    for (int i = beg + lane; i < end; i += 64) {
        int s = srcidx[i];
#pragma unroll
        for (int h = 0; h < H; ++h)
            lh[h] += __expf(leaky(sval[s * H + h] + dv[h]) - mh[h]);
    }
#pragma unroll
    for (int h = 0; h < H; ++h) {
        float l = lh[h];
        for (int off = 32; off; off >>= 1) l += __shfl_xor(l, off);
        l += __expf(es[h] - mh[h]);
        inv[h] = 1.f / (l + 1e-16f);
        acc[h] = __expf(es[h] - mh[h]) * inv[h] *
                 hw[(size_t)node * C + h * 64 + lane];
    }
    for (int i = beg; i < end; ++i) {
        int s = srcidx[i];
#pragma unroll
        for (int h = 0; h < H; ++h) {
            float e = leaky(sval[s * H + h] + dv[h]);
            float a = __expf(e - mh[h]) * inv[h];
            acc[h] += a * hw[(size_t)s * C + h * 64 + lane];
        }
    }
#pragma unroll
    for (int h = 0; h < H; ++h)
        gout[(size_t)node * C + h * 64 + lane] = acc[h];
}

// ------------------------------------------------- BatchNorm (batch stats)
__global__ void bn_partial(const float* __restrict__ gout, double* __restrict__ sums,
                           int Nn, int C)
{
    int t = threadIdx.x;
    int c = t % C, sub = t / C, nsub = blockDim.x / C;
    int rbase = blockIdx.x * 32;
    double s = 0.0, sq = 0.0;
    for (int r = rbase + sub; r < rbase + 32; r += nsub) {
        float x = gout[(size_t)r * C + c];
        s += x;
        sq += (double)x * x;
    }
    atomicAdd(&sums[c], s);
    atomicAdd(&sums[C + c], sq);
}

__global__ void bn_finalize(const double* __restrict__ sums, float* __restrict__ mu,
                            float* __restrict__ rstd, int Nn, int C)
{
    int c = threadIdx.x;
    if (c >= C) return;
    double m = sums[c] / Nn;
    double v = sums[C + c] / Nn - m * m;
    mu[c] = (float)m;
    rstd[c] = (float)(1.0 / sqrt(v + 1e-5));
}

__global__ void bn_res_act(const float* __restrict__ gout, const float* __restrict__ res,
                           const float* __restrict__ mu, const float* __restrict__ rstd,
                           const float* __restrict__ g, const float* __restrict__ be,
                           float* __restrict__ out, int total, int C)
{
    int i = blockIdx.x * blockDim.x + threadIdx.x;
    if (i >= total) return;
    int c = i & (C - 1);
    float v = (gout[i] - mu[c]) * rstd[c] * g[c] + be[c] + res[i];
    out[i] = leaky(v);
}

__global__ void jk_max(const float* __restrict__ a, const float* __restrict__ b,
                       const float* __restrict__ c, float* __restrict__ z, int total)
{
    int i = blockIdx.x * blockDim.x + threadIdx.x;
    if (i >= total) return;
    z[i] = fmaxf(fmaxf(a[i], b[i]), c[i]);
}

// ------------------------------------------------- per-dim |k| max (both heads)
__global__ void kmax_kernel(const float* __restrict__ kg, unsigned* __restrict__ kmax,
                            int N)
{
    const int c = threadIdx.x & 63, g = threadIdx.x >> 6;
    const int rows = N / (gridDim.x * 4);
    const int r0 = (blockIdx.x * 4 + g) * rows;
    float m = 0.f;
    for (int r = r0; r < r0 + rows; ++r)
        m = fmaxf(m, fabsf(kg[(size_t)r * 64 + c]));
    atomicMax(&kmax[c], __float_as_uint(m));
}

// ------------------------------------------------- full self-attention
// RQ=2 flash over a key chunk with FIXED per-row softmax shift
// (bound = sum_c |scale*q_c| * kmax_c; shift-invariance => no online max).
__global__ __launch_bounds__(256) void attn_partial(
    const float* __restrict__ qg, const float* __restrict__ kg,
    const float* __restrict__ vg, const unsigned* __restrict__ kmaxu,
    float* __restrict__ pl, __hip_bfloat16* __restrict__ pacc,
    int N, int nchunk, int chunksz)
{
    __shared__ __align__(16) float klds[128][32];
    __shared__ __align__(16) float vlds[128][32];
    const int head = blockIdx.z;
    const int row0 = blockIdx.y * 512 + threadIdx.x; // second row: +256
    const int chunk = blockIdx.x;
    const int kbase = chunk * chunksz;
    const float scale = 0.17677669529663687f; // 1/sqrt(32)

    float q0[32], q1[32];
    {
        const float* qp0 = qg + (size_t)row0 * 64 + head * 32;
        const float* qp1 = qp0 + 256 * 64;
#pragma unroll
        for (int c4 = 0; c4 < 8; ++c4) {
            float4 t0 = *(const float4*)(qp0 + c4 * 4);
            float4 t1 = *(const float4*)(qp1 + c4 * 4);
            q0[c4 * 4 + 0] = t0.x * scale; q0[c4 * 4 + 1] = t0.y * scale;
            q0[c4 * 4 + 2] = t0.z * scale; q0[c4 * 4 + 3] = t0.w * scale;
            q1[c4 * 4 + 0] = t1.x * scale; q1[c4 * 4 + 1] = t1.y * scale;
            q1[c4 * 4 + 2] = t1.z * scale; q1[c4 * 4 + 3] = t1.w * scale;
        }
    }
    float bound0 = 0.f, bound1 = 0.f;
#pragma unroll
    for (int c = 0; c < 32; ++c) {
        float km = __uint_as_float(kmaxu[head * 32 + c]);
        bound0 += fabsf(q0[c]) * km;
        bound1 += fabsf(q1[c]) * km;
    }
    float acc0[32] = {}, acc1[32] = {};
    float l0 = 0.f, l1 = 0.f;

    for (int t0 = kbase; t0 < kbase + chunksz; t0 += 128) {
        __syncthreads();
        for (int idx = threadIdx.x; idx < 128 * 8; idx += 256) {
            int r = idx >> 3, c4 = idx & 7;
            *(float4*)&klds[r][c4 * 4] =
                *(const float4*)&kg[(size_t)(t0 + r) * 64 + head * 32 + c4 * 4];
            *(float4*)&vlds[r][c4 * 4] =
                *(const float4*)&vg[(size_t)(t0 + r) * 64 + head * 32 + c4 * 4];
        }
        __syncthreads();
        for (int kk = 0; kk < 128; kk += 4) {
            float s0[4], s1[4];
#pragma unroll
            for (int i = 0; i < 4; ++i) {
                float a0 = 0.f, b0 = 0.f, a1 = 0.f, b1 = 0.f;
#pragma unroll
                for (int c4 = 0; c4 < 8; ++c4) {
                    float4 k4 = *(const float4*)&klds[kk + i][c4 * 4];
                    a0 += q0[c4 * 4 + 0] * k4.x + q0[c4 * 4 + 1] * k4.y;
                    b0 += q0[c4 * 4 + 2] * k4.z + q0[c4 * 4 + 3] * k4.w;
                    a1 += q1[c4 * 4 + 0] * k4.x + q1[c4 * 4 + 1] * k4.y;
                    b1 += q1[c4 * 4 + 2] * k4.z + q1[c4 * 4 + 3] * k4.w;
                }
                s0[i] = a0 + b0;
                s1[i] = a1 + b1;
            }
            float p0[4], p1[4];
#pragma unroll
            for (int i = 0; i < 4; ++i) {
                p0[i] = __expf(s0[i] - bound0);
                p1[i] = __expf(s1[i] - bound1);
            }
            l0 += (p0[0] + p0[1]) + (p0[2] + p0[3]);
            l1 += (p1[0] + p1[1]) + (p1[2] + p1[3]);
#pragma unroll
            for (int i = 0; i < 4; ++i) {
#pragma unroll
                for (int c4 = 0; c4 < 8; ++c4) {
                    float4 v4 = *(const float4*)&vlds[kk + i][c4 * 4];
                    acc0[c4 * 4 + 0] += p0[i] * v4.x; acc0[c4 * 4 + 1] += p0[i] * v4.y;
                    acc0[c4 * 4 + 2] += p0[i] * v4.z; acc0[c4 * 4 + 3] += p0[i] * v4.w;
                    acc1[c4 * 4 + 0] += p1[i] * v4.x; acc1[c4 * 4 + 1] += p1[i] * v4.y;
                    acc1[c4 * 4 + 2] += p1[i] * v4.z; acc1[c4 * 4 + 3] += p1[i] * v4.w;
                }
            }
        }
    }
    const size_t hr0 = (size_t)head * N + row0;
    const size_t hr1 = hr0 + 256;
    pl[hr0 * nchunk + chunk] = l0;
    pl[hr1 * nchunk + chunk] = l1;
    __hip_bfloat16* a0p = pacc + (hr0 * nchunk + chunk) * 32;
    __hip_bfloat16* a1p = pacc + (hr1 * nchunk + chunk) * 32;
#pragma unroll
    for (int c = 0; c < 32; ++c) {
        a0p[c] = __float2bfloat16(acc0[c]);
        a1p[c] = __float2bfloat16(acc1[c]);
    }
}

// all chunks of a row share the same shift -> plain sums, no max merge
__global__ void attn_combine(const float* __restrict__ pl,
                             const __hip_bfloat16* __restrict__ pacc,
                             float* __restrict__ og, int N, int nchunk)
{
    int i = blockIdx.x * blockDim.x + threadIdx.x;
    if (i >= 2 * N * 32) return;
    int hr = i >> 5, cc = i & 31;
    float l = 0.f, a = 0.f;
    for (int c = 0; c < nchunk; ++c) {
        l += pl[(size_t)hr * nchunk + c];
        a += __bfloat162float(pacc[((size_t)hr * nchunk + c) * 32 + cc]);
    }
    int head = hr / N, row = hr - head * N;
    og[(size_t)row * 64 + head * 32 + cc] = a / l;
}

// ----------------------------------------------------------------- host
extern "C" void kernel_launch(void* const* d_in, const int* in_sizes, int n_in,
                              void* d_out, int out_size, void* d_ws, size_t ws_size,
                              hipStream_t stream)
{
    const float* x = (const float*)d_in[0];
    const int* ei = (const int*)d_in[1];
    const float* w[3]   = {(const float*)d_in[2], (const float*)d_in[6],  (const float*)d_in[10]};
    const float* as_[3] = {(const float*)d_in[3], (const float*)d_in[7],  (const float*)d_in[11]};
    const float* ad_[3] = {(const float*)d_in[4], (const float*)d_in[8],  (const float*)d_in[12]};
    const float* rw[3]  = {(const float*)d_in[5], (const float*)d_in[9],  (const float*)d_in[13]};
    const float* p0 = (const float*)d_in[14];
    const float* p1 = (const float*)d_in[15];
    const float* qw = (const float*)d_in[16];
    const float* kw = (const float*)d_in[17];
    const float* vw = (const float*)d_in[18];
    const float* ow = (const float*)d_in[19];
    const float* m1w = (const float*)d_in[20];
    const float* m2w = (const float*)d_in[21];
    const float* m3w = (const float*)d_in[22];
    const float* g_[3]  = {(const float*)d_in[23], (const float*)d_in[24], (const float*)d_in[25]};
    const float* be_[3] = {(const float*)d_in[26], (const float*)d_in[27], (const float*)d_in[28]};
    // d_in[29..31] = b0,b1,b2: constant shift cancels inside BatchNorm -> unused
    const float* qb  = (const float*)d_in[32];
    const float* kb  = (const float*)d_in[33];
    const float* vb  = (const float*)d_in[34];
    const float* ob  = (const float*)d_in[35];
    const float* m1b = (const float*)d_in[36];
    const float* m2b = (const float*)d_in[37];
    const float* m3b = (const float*)d_in[38];

    const int N = in_sizes[0] / 64; // 8192
    const int E = in_sizes[1] / 2;  // 262144

    float* ws = (float*)d_ws;
    size_t off = 0;
    auto alloc = [&](size_t n) {
        float* p = ws + off;
        off += (n + 255) & ~(size_t)255;
        return p;
    };
    float* hw   = alloc((size_t)N * 256);
    float* res  = alloc((size_t)N * 256);
    float* gout = alloc((size_t)N * 256);
    float* h0   = alloc((size_t)N * 256);
    float* h1   = alloc((size_t)N * 256);
    float* h2   = alloc((size_t)N * 64);
    float* sval = alloc((size_t)N * 4);
    float* dval = alloc((size_t)N * 4);
    double* bnsum = (double*)alloc(1024); // 2*256 doubles
    float* mu   = alloc(256);
    float* rstd = alloc(256);
    int* cnt    = (int*)alloc(N);
    int* rowptr = (int*)alloc(N + 256);
    int* fill   = (int*)alloc(N);
    int* srcidx = (int*)alloc(E);
    unsigned* kmaxu = (unsigned*)alloc(64);
    // post-GAT aliases (hw/res/gout free by then)
    float* zq = hw;
    float* zk = hw + (size_t)N * 64;
    float* zv = hw + 2 * (size_t)N * 64;
    float* ao = hw + 3 * (size_t)N * 64;
    float* z  = gout;
    float* tA = res;
    float* tB = res + (size_t)N * 64;
    float* tC = res + 2 * (size_t)N * 64;
    // attention partials (live only between qkv-gemms and the ow-gemm):
    // pacc bf16: 2N*32*32 = 16.78M elems = 33.5MB = res+gout+h0+h1 exactly.
    // pl fp32: 2N*32 = 524288 floats = h2 exactly.
    const int NCHUNK = 32;
    __hip_bfloat16* pacc = (__hip_bfloat16*)res;
    float* pl = h2;

    auto gemm = [&](const float* A, const float* B, const float* bias, float* C,
                    int M, int Nc, int K, int act) {
        dim3 grid((Nc + 63) / 64, M / 64);
        gemm64<<<grid, 256, 0, stream>>>(A, B, bias, C, M, Nc, K, act);
    };

    // CSR build (edge_index constant across layers)
    hipMemsetAsync(cnt, 0, (size_t)N * 4, stream);
    csr_count<<<(E + 255) / 256, 256, 0, stream>>>(ei, cnt, E);
    csr_scan<<<1, 256, 0, stream>>>(cnt, rowptr, fill, N);
    csr_scatter<<<(E + 255) / 256, 256, 0, stream>>>(ei, fill, srcidx, E);

    const float* hin = x;
    int Kin = 64;
    float* houts[3] = {h0, h1, h2};
    int heads[3] = {4, 4, 1};

    for (int l = 0; l < 3; ++l) {
        int H = heads[l], C = H * 64;
        gemm(hin, w[l], nullptr, hw, N, C, Kin, 0);
        gemm(hin, rw[l], nullptr, res, N, C, Kin, 0);
        sd_kernel<<<(N * H + 255) / 256, 256, 0, stream>>>(hw, as_[l], ad_[l], sval, dval, N, H);
        if (H == 4)
            gat_gather<4><<<N / 4, 256, 0, stream>>>(rowptr, srcidx, hw, sval, dval, gout, N);
        else
            gat_gather<1><<<N / 4, 256, 0, stream>>>(rowptr, srcidx, hw, sval, dval, gout, N);
        hipMemsetAsync(bnsum, 0, (size_t)2 * C * 8, stream);
        bn_partial<<<N / 32, 256, 0, stream>>>(gout, bnsum, N, C);
        bn_finalize<<<1, 256, 0, stream>>>(bnsum, mu, rstd, N, C);
        bn_res_act<<<((size_t)N * C) / 256, 256, 0, stream>>>(gout, res, mu, rstd, g_[l], be_[l], houts[l], N * C, C);
        hin = houts[l];
        Kin = C;
    }

    // JumpingKnowledge max
    gemm(h0, p0, nullptr, tA, N, 64, 256, 0);
    gemm(h1, p1, nullptr, tB, N, 64, 256, 0);
    jk_max<<<((size_t)N * 64) / 256, 256, 0, stream>>>(tA, tB, h2, z, N * 64);

    // self-attention (flash, key-chunked, RQ=2, fixed-shift softmax)
    gemm(z, qw, qb, zq, N, 64, 64, 0);
    gemm(z, kw, kb, zk, N, 64, 64, 0);
    gemm(z, vw, vb, zv, N, 64, 64, 0);
    hipMemsetAsync(kmaxu, 0, 64 * 4, stream);
    kmax_kernel<<<32, 256, 0, stream>>>(zk, kmaxu, N);
    attn_partial<<<dim3(NCHUNK, N / 512, 2), 256, 0, stream>>>(
        zq, zk, zv, kmaxu, pl, pacc, N, NCHUNK, N / NCHUNK);
    attn_combine<<<(2 * N * 32 + 255) / 256, 256, 0, stream>>>(pl, pacc, ao, N, NCHUNK);
    gemm(ao, ow, ob, tA, N, 64, 64, 0);

    // MLP head
    gemm(tA, m1w, m1b, tB, N, 64, 64, 1);
    gemm(tB, m2w, m2b, tC, N, 32, 64, 1);
    gemm(tC, m3w, m3b, (float*)d_out, N, 10, 32, 0);
}

// Round 6
// 470.938 us; speedup vs baseline: 1.6660x; 1.6660x over previous
//
#include <hip/hip_runtime.h>
#include <hip/hip_bf16.h>

// NeuronGAT forward. Round 5:
//  - attn rewritten on bf16 MFMA (mfma_f32_32x32x16_bf16), swapped QK^T,
//    fixed-bound softmax (per-lane-uniform => no cross-lane max), PV via
//    lane^32 shuffle repack. No LDS. Q/K/V pre-converted to bf16 frag layouts.
//  - gemm_skinny restored for N<=64 (gemm64-everywhere cost ~45us in r4->r5).

#define NEG 0.2f

__device__ __forceinline__ float leaky(float v) { return v > 0.f ? v : NEG * v; }

// round-to-nearest-even fp32 -> bf16 bits
__device__ __forceinline__ unsigned bf16u(float x) {
    unsigned u = __float_as_uint(x);
    u += 0x7FFFu + ((u >> 16) & 1u);
    return u >> 16;
}

typedef __attribute__((ext_vector_type(8))) short bf16x8;   // 8 bf16 = 4 VGPR
typedef __attribute__((ext_vector_type(16))) float f32x16;  // MFMA C/D
typedef __attribute__((ext_vector_type(4))) unsigned uint4v;

// ---------------------------------------------------------------- GEMM 64x64
// C[M,N] = act(A[M,K] @ B[K,N] + bias). M%64==0, K%32==0.
__global__ __launch_bounds__(256) void gemm64(
    const float* __restrict__ A, const float* __restrict__ B,
    const float* __restrict__ bias, float* __restrict__ C,
    int M, int N, int K, int act)
{
    __shared__ __align__(16) float As[32][64];
    __shared__ __align__(16) float Bs[32][64];
    const int tx = threadIdx.x & 15, ty = threadIdx.x >> 4;
    const int row0 = blockIdx.y * 64, col0 = blockIdx.x * 64;
    const int ar = threadIdx.x & 63, akq = threadIdx.x >> 6;
    const int bc = threadIdx.x & 15, bk = threadIdx.x >> 4;
    float acc[4][4] = {};
    for (int k0 = 0; k0 < K; k0 += 32) {
        {
            const float* ap = A + (size_t)(row0 + ar) * K + k0 + akq * 8;
            float4 a0 = *(const float4*)ap;
            float4 a1 = *(const float4*)(ap + 4);
            int kb = akq * 8;
            As[kb + 0][ar] = a0.x; As[kb + 1][ar] = a0.y;
            As[kb + 2][ar] = a0.z; As[kb + 3][ar] = a0.w;
            As[kb + 4][ar] = a1.x; As[kb + 5][ar] = a1.y;
            As[kb + 6][ar] = a1.z; As[kb + 7][ar] = a1.w;
        }
#pragma unroll
        for (int j = 0; j < 2; ++j) {
            int kk = bk + j * 16;
            int col = col0 + bc * 4;
            float4 b;
            if (col + 3 < N) {
                b = *(const float4*)&B[(size_t)(k0 + kk) * N + col];
            } else {
                b.x = col < N ? B[(size_t)(k0 + kk) * N + col] : 0.f;
                b.y = col + 1 < N ? B[(size_t)(k0 + kk) * N + col + 1] : 0.f;
                b.z = col + 2 < N ? B[(size_t)(k0 + kk) * N + col + 2] : 0.f;
                b.w = col + 3 < N ? B[(size_t)(k0 + kk) * N + col + 3] : 0.f;
            }
            *(float4*)&Bs[kk][bc * 4] = b;
        }
        __syncthreads();
#pragma unroll
        for (int kk = 0; kk < 32; ++kk) {
            float4 a4 = *(const float4*)&As[kk][ty * 4];
            float4 b4 = *(const float4*)&Bs[kk][tx * 4];
            float a[4] = {a4.x, a4.y, a4.z, a4.w};
            float b[4] = {b4.x, b4.y, b4.z, b4.w};
#pragma unroll
            for (int i = 0; i < 4; ++i)
#pragma unroll
                for (int j = 0; j < 4; ++j) acc[i][j] += a[i] * b[j];
        }
        __syncthreads();
    }
#pragma unroll
    for (int i = 0; i < 4; ++i) {
        int r = row0 + ty * 4 + i;
#pragma unroll
        for (int j = 0; j < 4; ++j) {
            int c = col0 + tx * 4 + j;
            if (c < N) {
                float v = acc[i][j] + (bias ? bias[c] : 0.f);
                if (act) v = leaky(v);
                C[(size_t)r * N + c] = v;
            }
        }
    }
}

// ------------------------------------------------- GEMM skinny (N <= 64)
__global__ __launch_bounds__(256) void gemm_skinny(
    const float* __restrict__ A, const float* __restrict__ B,
    const float* __restrict__ bias, float* __restrict__ C,
    int M, int N, int K, int act)
{
    __shared__ __align__(16) float As[16][68];
    __shared__ __align__(16) float Bs[64][64];
    const int rr = threadIdx.x >> 4, c4 = threadIdx.x & 15;
    const int row0 = blockIdx.x * 16;
    float acc[4] = {};
    for (int k0 = 0; k0 < K; k0 += 64) {
        {
            int k = k0 + c4 * 4;
            float4 a = {0.f, 0.f, 0.f, 0.f};
            const float* ap = &A[(size_t)(row0 + rr) * K + k];
            if (k + 3 < K) a = *(const float4*)ap;
            else {
                if (k < K) a.x = ap[0];
                if (k + 1 < K) a.y = ap[1];
                if (k + 2 < K) a.z = ap[2];
                if (k + 3 < K) a.w = ap[3];
            }
            *(float4*)&As[rr][c4 * 4] = a;
        }
#pragma unroll
        for (int j = 0; j < 4; ++j) {
            int kk = rr + j * 16;
            int col = c4 * 4;
            float4 b = {0.f, 0.f, 0.f, 0.f};
            if (k0 + kk < K) {
                const float* bp = &B[(size_t)(k0 + kk) * N + col];
                if (col + 3 < N) b = *(const float4*)bp;
                else {
                    if (col < N) b.x = bp[0];
                    if (col + 1 < N) b.y = bp[1];
                    if (col + 2 < N) b.z = bp[2];
                    if (col + 3 < N) b.w = bp[3];
                }
            }
            *(float4*)&Bs[kk][col] = b;
        }
        __syncthreads();
#pragma unroll
        for (int kk = 0; kk < 64; ++kk) {
            float a = As[rr][kk];
            float4 b4 = *(const float4*)&Bs[kk][c4 * 4];
            acc[0] += a * b4.x; acc[1] += a * b4.y;
            acc[2] += a * b4.z; acc[3] += a * b4.w;
        }
        __syncthreads();
    }
    int row = row0 + rr, col = c4 * 4;
#pragma unroll
    for (int j = 0; j < 4; ++j) {
        if (col + j < N) {
            float v = acc[j] + (bias ? bias[col + j] : 0.f);
            if (act) v = leaky(v);
            C[(size_t)row * N + col + j] = v;
        }
    }
}

// ------------------------------------------------- GAT attention scores
__global__ void sd_kernel(const float* __restrict__ hw, const float* __restrict__ a_s,
                          const float* __restrict__ a_d, float* __restrict__ sval,
                          float* __restrict__ dval, int Nn, int H)
{
    int i = blockIdx.x * blockDim.x + threadIdx.x;
    if (i >= Nn * H) return;
    int n = i / H, h = i - n * H;
    const float4* row = (const float4*)(hw + (size_t)n * H * 64 + h * 64);
    const float4* as4 = (const float4*)(a_s + h * 64);
    const float4* ad4 = (const float4*)(a_d + h * 64);
    float s = 0.f, d = 0.f;
#pragma unroll
    for (int c = 0; c < 16; ++c) {
        float4 x = row[c], a = as4[c], b = ad4[c];
        s += x.x * a.x + x.y * a.y + x.z * a.z + x.w * a.w;
        d += x.x * b.x + x.y * b.y + x.z * b.z + x.w * b.w;
    }
    sval[i] = s;
    dval[i] = d;
}

// ------------------------------------------------- CSR build (by dst)
__global__ void csr_count(const int* __restrict__ ei, int* __restrict__ cnt, int E) {
    int i = blockIdx.x * 256 + threadIdx.x;
    if (i < E) atomicAdd(&cnt[ei[E + i]], 1);
}

__global__ __launch_bounds__(256) void csr_scan(const int* __restrict__ cnt,
                                                int* __restrict__ rowptr,
                                                int* __restrict__ fill, int Nn)
{
    __shared__ int part[256];
    int t = threadIdx.x;
    int loc[32];
    int s = 0;
#pragma unroll
    for (int j = 0; j < 32; ++j) { loc[j] = s; s += cnt[t * 32 + j]; }
    part[t] = s;
    __syncthreads();
    for (int d = 1; d < 256; d <<= 1) {
        int v = (t >= d) ? part[t - d] : 0;
        __syncthreads();
        part[t] += v;
        __syncthreads();
    }
    int off = (t > 0) ? part[t - 1] : 0;
#pragma unroll
    for (int j = 0; j < 32; ++j) {
        int v = off + loc[j];
        rowptr[t * 32 + j] = v;
        fill[t * 32 + j] = v;
    }
    if (t == 255) rowptr[Nn] = part[255];
}

__global__ void csr_scatter(const int* __restrict__ ei, int* __restrict__ fill,
                            int* __restrict__ srcidx, int E) {
    int i = blockIdx.x * 256 + threadIdx.x;
    if (i < E) {
        int d = ei[E + i];
        int p = atomicAdd(&fill[d], 1);
        srcidx[p] = ei[i];
    }
}

// ------------------------------------------------- fused GAT gather
template <int H>
__global__ __launch_bounds__(256) void gat_gather(
    const int* __restrict__ rowptr, const int* __restrict__ srcidx,
    const float* __restrict__ hw, const float* __restrict__ sval,
    const float* __restrict__ dval, float* __restrict__ gout, int Nn)
{
    const int node = blockIdx.x * 4 + (threadIdx.x >> 6);
    const int lane = threadIdx.x & 63;
    const int beg = rowptr[node], end = rowptr[node + 1];
    const int C = H * 64;
    float dv[H], es[H], mh[H], lh[H], inv[H], acc[H];
#pragma unroll
    for (int h = 0; h < H; ++h) {
        dv[h] = dval[node * H + h];
        es[h] = leaky(sval[node * H + h] + dv[h]);
        mh[h] = -1e30f;
        lh[h] = 0.f;
    }
    for (int i = beg + lane; i < end; i += 64) {
        int s = srcidx[i];
#pragma unroll
        for (int h = 0; h < H; ++h)
            mh[h] = fmaxf(mh[h], leaky(sval[s * H + h] + dv[h]));
    }
#pragma unroll
    for (int h = 0; h < H; ++h) {
        float m = mh[h];
        for (int off = 32; off; off >>= 1) m = fmaxf(m, __shfl_xor(m, off));
        mh[h] = fmaxf(m, es[h]);
    }
    for (int i = beg + lane; i < end; i += 64) {
        int s = srcidx[i];
#pragma unroll
        for (int h = 0; h < H; ++h)
            lh[h] += __expf(leaky(sval[s * H + h] + dv[h]) - mh[h]);
    }
#pragma unroll
    for (int h = 0; h < H; ++h) {
        float l = lh[h];
        for (int off = 32; off; off >>= 1) l += __shfl_xor(l, off);
        l += __expf(es[h] - mh[h]);
        inv[h] = 1.f / (l + 1e-16f);
        acc[h] = __expf(es[h] - mh[h]) * inv[h] *
                 hw[(size_t)node * C + h * 64 + lane];
    }
    for (int i = beg; i < end; ++i) {
        int s = srcidx[i];
#pragma unroll
        for (int h = 0; h < H; ++h) {
            float e = leaky(sval[s * H + h] + dv[h]);
            float a = __expf(e - mh[h]) * inv[h];
            acc[h] += a * hw[(size_t)s * C + h * 64 + lane];
        }
    }
#pragma unroll
    for (int h = 0; h < H; ++h)
        gout[(size_t)node * C + h * 64 + lane] = acc[h];
}

// ------------------------------------------------- BatchNorm (batch stats)
__global__ void bn_partial(const float* __restrict__ gout, double* __restrict__ sums,
                           int Nn, int C)
{
    int t = threadIdx.x;
    int c = t % C, sub = t / C, nsub = blockDim.x / C;
    int rbase = blockIdx.x * 32;
    double s = 0.0, sq = 0.0;
    for (int r = rbase + sub; r < rbase + 32; r += nsub) {
        float x = gout[(size_t)r * C + c];
        s += x;
        sq += (double)x * x;
    }
    atomicAdd(&sums[c], s);
    atomicAdd(&sums[C + c], sq);
}

__global__ void bn_finalize(const double* __restrict__ sums, float* __restrict__ mu,
                            float* __restrict__ rstd, int Nn, int C)
{
    int c = threadIdx.x;
    if (c >= C) return;
    double m = sums[c] / Nn;
    double v = sums[C + c] / Nn - m * m;
    mu[c] = (float)m;
    rstd[c] = (float)(1.0 / sqrt(v + 1e-5));
}

__global__ void bn_res_act(const float* __restrict__ gout, const float* __restrict__ res,
                           const float* __restrict__ mu, const float* __restrict__ rstd,
                           const float* __restrict__ g, const float* __restrict__ be,
                           float* __restrict__ out, int total, int C)
{
    int i = blockIdx.x * blockDim.x + threadIdx.x;
    if (i >= total) return;
    int c = i & (C - 1);
    float v = (gout[i] - mu[c]) * rstd[c] * g[c] + be[c] + res[i];
    out[i] = leaky(v);
}

__global__ void jk_max(const float* __restrict__ a, const float* __restrict__ b,
                       const float* __restrict__ c, float* __restrict__ z, int total)
{
    int i = blockIdx.x * blockDim.x + threadIdx.x;
    if (i >= total) return;
    z[i] = fmaxf(fmaxf(a[i], b[i]), c[i]);
}

// ------------------------------------------------- per-dim |k| max (both heads)
__global__ void kmax_kernel(const float* __restrict__ kg, unsigned* __restrict__ kmax,
                            int N)
{
    const int c = threadIdx.x & 63, g = threadIdx.x >> 6;
    const int rows = N / (gridDim.x * 4);
    const int r0 = (blockIdx.x * 4 + g) * rows;
    float m = 0.f;
    for (int r = r0; r < r0 + rows; ++r)
        m = fmaxf(m, fabsf(kg[(size_t)r * 64 + c]));
    atomicMax(&kmax[c], __float_as_uint(m));
}

// ------------------------------------------------- attn prep: Qb/Kb bf16 + bound
// Qb[h][row][32] = bf16(q*scale); Kb likewise (unscaled); bound = sum |q*s|*kmax.
__global__ void qk_prep(const float* __restrict__ zq, const float* __restrict__ zk,
                        const unsigned* __restrict__ kmaxu,
                        __hip_bfloat16* __restrict__ Qb, __hip_bfloat16* __restrict__ Kb,
                        float* __restrict__ bound, int N)
{
    int idx = blockIdx.x * 256 + threadIdx.x;
    if (idx >= 2 * N) return;
    int h = idx / N, row = idx - h * N;
    const float scale = 0.17677669529663687f;
    const float* qp = zq + (size_t)row * 64 + h * 32;
    const float* kp = zk + (size_t)row * 64 + h * 32;
    float b = 0.f;
    unsigned qo[16], ko[16];
#pragma unroll
    for (int i = 0; i < 16; ++i) {
        float q0 = qp[2 * i] * scale, q1 = qp[2 * i + 1] * scale;
        float k0 = kp[2 * i], k1 = kp[2 * i + 1];
        b += fabsf(q0) * __uint_as_float(kmaxu[h * 32 + 2 * i]);
        b += fabsf(q1) * __uint_as_float(kmaxu[h * 32 + 2 * i + 1]);
        qo[i] = bf16u(q0) | (bf16u(q1) << 16);
        ko[i] = bf16u(k0) | (bf16u(k1) << 16);
    }
    uint4* qd = (uint4*)(Qb + (size_t)idx * 32);
    uint4* kd = (uint4*)(Kb + (size_t)idx * 32);
#pragma unroll
    for (int i = 0; i < 4; ++i) {
        qd[i] = make_uint4(qo[4 * i], qo[4 * i + 1], qo[4 * i + 2], qo[4 * i + 3]);
        kd[i] = make_uint4(ko[4 * i], ko[4 * i + 1], ko[4 * i + 2], ko[4 * i + 3]);
    }
    bound[idx] = b;
}

// V into the PV A-fragment layout: Vf[h][g][lane][j] = V[g*16+(lane>>5)*8+j][h*32+(lane&31)]
__global__ void v_prep(const float* __restrict__ zv, __hip_bfloat16* __restrict__ Vf,
                       int N)
{
    int idx = blockIdx.x * 256 + threadIdx.x;
    int total = 2 * (N >> 4) * 64;
    if (idx >= total) return;
    int lane = idx & 63;
    int g = (idx >> 6) % (N >> 4);
    int h = (idx >> 6) / (N >> 4);
    int kb = g * 16 + (lane >> 5) * 8;
    int d = (lane & 31) + h * 32;
    unsigned o[4];
#pragma unroll
    for (int i = 0; i < 4; ++i) {
        unsigned u0 = bf16u(zv[(size_t)(kb + 2 * i) * 64 + d]);
        unsigned u1 = bf16u(zv[(size_t)(kb + 2 * i + 1) * 64 + d]);
        o[i] = u0 | (u1 << 16);
    }
    *(uint4*)(Vf + (size_t)idx * 8) = make_uint4(o[0], o[1], o[2], o[3]);
}

// ------------------------------------------------- MFMA full self-attention
// One wave per (32-q tile, key chunk). Swapped QK^T: S^T[k][q] = mfma(K,Q) so
// C/D layout (col=lane&31=q) makes the fixed-bound exp per-lane-uniform.
// PV: O^T[d][q] += V^T-frag x P^T-frag; P^T built via lane^32 shuffle repack.
__global__ __launch_bounds__(256) void attn_mfma(
    const __hip_bfloat16* __restrict__ Qb, const __hip_bfloat16* __restrict__ Kb,
    const __hip_bfloat16* __restrict__ Vf, const float* __restrict__ bound,
    float* __restrict__ pl, __hip_bfloat16* __restrict__ pacc,
    int N, int nchunk, int chunksz)
{
    const int lane = threadIdx.x & 63;
    const int wid = threadIdx.x >> 6;
    const int hi = lane >> 5, lq = lane & 31;
    const int chunk = blockIdx.x;
    const int qtile = blockIdx.y * 4 + wid;        // [0, 2N/32)
    const int head = qtile / (N >> 5);
    const int q0 = (qtile % (N >> 5)) * 32;
    const int kbase = chunk * chunksz;

    const size_t qrow = (size_t)head * N + q0 + lq;
    const bf16x8 qf0 = *(const bf16x8*)(Qb + qrow * 32 + hi * 8);        // dims 0-15
    const bf16x8 qf1 = *(const bf16x8*)(Qb + qrow * 32 + hi * 8 + 16);   // dims 16-31
    const float bnd = bound[qrow];

    f32x16 oacc;
#pragma unroll
    for (int r = 0; r < 16; ++r) oacc[r] = 0.f;
    float lsum = 0.f;

    for (int kt = kbase; kt < kbase + chunksz; kt += 32) {
        const size_t krow = (size_t)head * N + kt + lq;
        const bf16x8 kf0 = *(const bf16x8*)(Kb + krow * 32 + hi * 8);
        const bf16x8 kf1 = *(const bf16x8*)(Kb + krow * 32 + hi * 8 + 16);
        f32x16 s;
#pragma unroll
        for (int r = 0; r < 16; ++r) s[r] = 0.f;
        s = __builtin_amdgcn_mfma_f32_32x32x16_bf16(kf0, qf0, s, 0, 0, 0);
        s = __builtin_amdgcn_mfma_f32_32x32x16_bf16(kf1, qf1, s, 0, 0, 0);
        // s[r] = S^T[k = (r&3)+8*(r>>2)+4*hi][q = lq] (scaled; bound pre-subtracted)
        const __hip_bfloat16* vfb =
            Vf + (((size_t)head * (N >> 4) + (kt >> 4)) * 64 + lane) * 8;
        const bf16x8 vf0 = *(const bf16x8*)vfb;            // keys kt..kt+15
        const bf16x8 vf1 = *(const bf16x8*)(vfb + 64 * 8); // keys kt+16..kt+31

        float p[16];
#pragma unroll
        for (int r = 0; r < 16; ++r) p[r] = __expf(s[r] - bnd);
        float ls = 0.f;
#pragma unroll
        for (int r = 0; r < 16; ++r) ls += p[r];
        lsum += ls;

        unsigned wpk[8];
#pragma unroll
        for (int i = 0; i < 8; ++i)
            wpk[i] = bf16u(p[2 * i]) | (bf16u(p[2 * i + 1]) << 16);
        unsigned ws[8];
#pragma unroll
        for (int i = 0; i < 8; ++i) ws[i] = (unsigned)__shfl_xor((int)wpk[i], 32);
        // B-frag for PV1 (keys kt+0..15): lane needs P[k=hi*8+j][q]
        uint4v b1, b2;
        b1[0] = hi ? ws[2] : wpk[0];
        b1[1] = hi ? ws[3] : wpk[1];
        b1[2] = hi ? wpk[2] : ws[0];
        b1[3] = hi ? wpk[3] : ws[1];
        b2[0] = hi ? ws[6] : wpk[4];
        b2[1] = hi ? ws[7] : wpk[5];
        b2[2] = hi ? wpk[6] : ws[4];
        b2[3] = hi ? wpk[7] : ws[5];
        oacc = __builtin_amdgcn_mfma_f32_32x32x16_bf16(
            vf0, __builtin_bit_cast(bf16x8, b1), oacc, 0, 0, 0);
        oacc = __builtin_amdgcn_mfma_f32_32x32x16_bf16(
            vf1, __builtin_bit_cast(bf16x8, b2), oacc, 0, 0, 0);
    }
    // lane and lane^32 each hold half the keys for the same q
    lsum += __shfl_xor(lsum, 32);
    const size_t hr = (size_t)head * N + q0 + lq;
    if (hi == 0) pl[hr * nchunk + chunk] = lsum;
    __hip_bfloat16* pb = pacc + (hr * nchunk + chunk) * 32;
#pragma unroll
    for (int rg = 0; rg < 4; ++rg) {
        // regs 4rg..4rg+3 hold d = 8*rg + 4*hi + 0..3 for q=lq
        unsigned lo = bf16u(oacc[rg * 4 + 0]) | (bf16u(oacc[rg * 4 + 1]) << 16);
        unsigned hw2 = bf16u(oacc[rg * 4 + 2]) | (bf16u(oacc[rg * 4 + 3]) << 16);
        *(uint2*)(pb + rg * 8 + hi * 4) = make_uint2(lo, hw2);
    }
}

// all chunks share the same per-row shift -> plain sums
__global__ void attn_combine(const float* __restrict__ pl,
                             const __hip_bfloat16* __restrict__ pacc,
                             float* __restrict__ og, int N, int nchunk)
{
    int i = blockIdx.x * blockDim.x + threadIdx.x;
    if (i >= 2 * N * 32) return;
    int hr = i >> 5, cc = i & 31;
    float l = 0.f, a = 0.f;
    for (int c = 0; c < nchunk; ++c) {
        l += pl[(size_t)hr * nchunk + c];
        a += __bfloat162float(pacc[((size_t)hr * nchunk + c) * 32 + cc]);
    }
    int head = hr / N, row = hr - head * N;
    og[(size_t)row * 64 + head * 32 + cc] = a / l;
}

// ----------------------------------------------------------------- host
extern "C" void kernel_launch(void* const* d_in, const int* in_sizes, int n_in,
                              void* d_out, int out_size, void* d_ws, size_t ws_size,
                              hipStream_t stream)
{
    const float* x = (const float*)d_in[0];
    const int* ei = (const int*)d_in[1];
    const float* w[3]   = {(const float*)d_in[2], (const float*)d_in[6],  (const float*)d_in[10]};
    const float* as_[3] = {(const float*)d_in[3], (const float*)d_in[7],  (const float*)d_in[11]};
    const float* ad_[3] = {(const float*)d_in[4], (const float*)d_in[8],  (const float*)d_in[12]};
    const float* rw[3]  = {(const float*)d_in[5], (const float*)d_in[9],  (const float*)d_in[13]};
    const float* p0 = (const float*)d_in[14];
    const float* p1 = (const float*)d_in[15];
    const float* qw = (const float*)d_in[16];
    const float* kw = (const float*)d_in[17];
    const float* vw = (const float*)d_in[18];
    const float* ow = (const float*)d_in[19];
    const float* m1w = (const float*)d_in[20];
    const float* m2w = (const float*)d_in[21];
    const float* m3w = (const float*)d_in[22];
    const float* g_[3]  = {(const float*)d_in[23], (const float*)d_in[24], (const float*)d_in[25]};
    const float* be_[3] = {(const float*)d_in[26], (const float*)d_in[27], (const float*)d_in[28]};
    // d_in[29..31] = b0,b1,b2: constant shift cancels inside BatchNorm -> unused
    const float* qb  = (const float*)d_in[32];
    const float* kb  = (const float*)d_in[33];
    const float* vb  = (const float*)d_in[34];
    const float* ob  = (const float*)d_in[35];
    const float* m1b = (const float*)d_in[36];
    const float* m2b = (const float*)d_in[37];
    const float* m3b = (const float*)d_in[38];

    const int N = in_sizes[0] / 64; // 8192
    const int E = in_sizes[1] / 2;  // 262144

    float* ws = (float*)d_ws;
    size_t off = 0;
    auto alloc = [&](size_t n) {
        float* p = ws + off;
        off += (n + 255) & ~(size_t)255;
        return p;
    };
    float* hw   = alloc((size_t)N * 256);
    float* res  = alloc((size_t)N * 256);
    float* gout = alloc((size_t)N * 256);
    float* h0   = alloc((size_t)N * 256);
    float* h1   = alloc((size_t)N * 256);
    float* h2   = alloc((size_t)N * 64);
    float* sval = alloc((size_t)N * 4);
    float* dval = alloc((size_t)N * 4);
    double* bnsum = (double*)alloc(1024);
    float* mu   = alloc(256);
    float* rstd = alloc(256);
    int* cnt    = (int*)alloc(N);
    int* rowptr = (int*)alloc(N + 256);
    int* fill   = (int*)alloc(N);
    int* srcidx = (int*)alloc(E);
    unsigned* kmaxu = (unsigned*)alloc(64);
    // post-GAT aliases (hw dead after layer 3)
    float* zq = hw;
    float* zk = hw + (size_t)N * 64;
    float* zv = hw + 2 * (size_t)N * 64;
    float* ao = hw + 3 * (size_t)N * 64;
    float* z  = gout;
    float* tA = res;
    float* tB = res + (size_t)N * 64;
    float* tC = res + 2 * (size_t)N * 64;
    // attn buffers: Qb/Kb/Vf/bound in h0 (dead after JK); pacc=res; pl=h2.
    const int NCHUNK = 8;
    __hip_bfloat16* Qb = (__hip_bfloat16*)h0;
    __hip_bfloat16* Kb = Qb + (size_t)2 * N * 32;
    __hip_bfloat16* Vf = Kb + (size_t)2 * N * 32;
    float* boundArr = (float*)(Vf + (size_t)2 * N * 32);
    __hip_bfloat16* pacc = (__hip_bfloat16*)res;
    float* pl = h2;

    auto gemm = [&](const float* A, const float* B, const float* bias, float* C,
                    int M, int Nc, int K, int act) {
        if (Nc <= 64) {
            gemm_skinny<<<M / 16, 256, 0, stream>>>(A, B, bias, C, M, Nc, K, act);
        } else {
            dim3 grid((Nc + 63) / 64, M / 64);
            gemm64<<<grid, 256, 0, stream>>>(A, B, bias, C, M, Nc, K, act);
        }
    };

    // CSR build (edge_index constant across layers)
    hipMemsetAsync(cnt, 0, (size_t)N * 4, stream);
    csr_count<<<(E + 255) / 256, 256, 0, stream>>>(ei, cnt, E);
    csr_scan<<<1, 256, 0, stream>>>(cnt, rowptr, fill, N);
    csr_scatter<<<(E + 255) / 256, 256, 0, stream>>>(ei, fill, srcidx, E);

    const float* hin = x;
    int Kin = 64;
    float* houts[3] = {h0, h1, h2};
    int heads[3] = {4, 4, 1};

    for (int l = 0; l < 3; ++l) {
        int H = heads[l], C = H * 64;
        gemm(hin, w[l], nullptr, hw, N, C, Kin, 0);
        gemm(hin, rw[l], nullptr, res, N, C, Kin, 0);
        sd_kernel<<<(N * H + 255) / 256, 256, 0, stream>>>(hw, as_[l], ad_[l], sval, dval, N, H);
        if (H == 4)
            gat_gather<4><<<N / 4, 256, 0, stream>>>(rowptr, srcidx, hw, sval, dval, gout, N);
        else
            gat_gather<1><<<N / 4, 256, 0, stream>>>(rowptr, srcidx, hw, sval, dval, gout, N);
        hipMemsetAsync(bnsum, 0, (size_t)2 * C * 8, stream);
        bn_partial<<<N / 32, 256, 0, stream>>>(gout, bnsum, N, C);
        bn_finalize<<<1, 256, 0, stream>>>(bnsum, mu, rstd, N, C);
        bn_res_act<<<((size_t)N * C) / 256, 256, 0, stream>>>(gout, res, mu, rstd, g_[l], be_[l], houts[l], N * C, C);
        hin = houts[l];
        Kin = C;
    }

    // JumpingKnowledge max
    gemm(h0, p0, nullptr, tA, N, 64, 256, 0);
    gemm(h1, p1, nullptr, tB, N, 64, 256, 0);
    jk_max<<<((size_t)N * 64) / 256, 256, 0, stream>>>(tA, tB, h2, z, N * 64);

    // self-attention (bf16 MFMA flash, fixed-shift softmax, key-chunked)
    gemm(z, qw, qb, zq, N, 64, 64, 0);
    gemm(z, kw, kb, zk, N, 64, 64, 0);
    gemm(z, vw, vb, zv, N, 64, 64, 0);
    hipMemsetAsync(kmaxu, 0, 64 * 4, stream);
    kmax_kernel<<<32, 256, 0, stream>>>(zk, kmaxu, N);
    qk_prep<<<(2 * N + 255) / 256, 256, 0, stream>>>(zq, zk, kmaxu, Qb, Kb, boundArr, N);
    v_prep<<<(2 * (N >> 4) * 64 + 255) / 256, 256, 0, stream>>>(zv, Vf, N);
    attn_mfma<<<dim3(NCHUNK, (2 * N / 32) / 4), 256, 0, stream>>>(
        Qb, Kb, Vf, boundArr, pl, pacc, N, NCHUNK, N / NCHUNK);
    attn_combine<<<(2 * N * 32 + 255) / 256, 256, 0, stream>>>(pl, pacc, ao, N, NCHUNK);
    gemm(ao, ow, ob, tA, N, 64, 64, 0);

    // MLP head
    gemm(tA, m1w, m1b, tB, N, 64, 64, 1);
    gemm(tB, m2w, m2b, tC, N, 32, 64, 1);
    gemm(tC, m3w, m3b, (float*)d_out, N, 10, 32, 0);
}

// Round 7
// 458.204 us; speedup vs baseline: 1.7123x; 1.0278x over previous
//
#include <hip/hip_runtime.h>
#include <hip/hip_bf16.h>

// NeuronGAT forward. Round 6:
//  - ALL GEMMs moved to bf16 MFMA with split-precision (hi+lo) 3-product
//    scheme: A@B = Ahi.Bhi + Ahi.Blo + Alo.Bhi (fp32 accum) -> ~fp32 accuracy
//    at bf16 MFMA speed. Fragment layout identical to the r5-verified attn.
//  - splits fused into producers (bn_res_act, jk_max, attn_combine, gemm
//    epilogue); weights batch-split once; only x and h0@JK need standalone
//    split launches.
//  - attn kernel unchanged from r5 (49us, verified).

#define NEG 0.2f

__device__ __forceinline__ float leaky(float v) { return v > 0.f ? v : NEG * v; }

// round-to-nearest-even fp32 -> bf16 bits
__device__ __forceinline__ unsigned bf16u(float x) {
    unsigned u = __float_as_uint(x);
    u += 0x7FFFu + ((u >> 16) & 1u);
    return u >> 16;
}

typedef __attribute__((ext_vector_type(8))) short bf16x8;   // 8 bf16 = 4 VGPR
typedef __attribute__((ext_vector_type(16))) float f32x16;  // MFMA C/D
typedef __attribute__((ext_vector_type(4))) unsigned uint4v;

// ------------------------------------------------- split helpers
__device__ __forceinline__ void split1(float v, unsigned& hb, unsigned& lb) {
    hb = bf16u(v);
    float hf = __uint_as_float(hb << 16);
    lb = bf16u(v - hf);
}

// fp32 [*] -> hi/lo bf16, vectorized by 4
__global__ void split_rows(const float* __restrict__ in,
                           unsigned short* __restrict__ hi,
                           unsigned short* __restrict__ lo, int total4)
{
    int i = blockIdx.x * 256 + threadIdx.x;
    if (i >= total4) return;
    float4 v = ((const float4*)in)[i];
    float vv[4] = {v.x, v.y, v.z, v.w};
    ushort4 h, l;
#pragma unroll
    for (int j = 0; j < 4; ++j) {
        unsigned hb, lb;
        split1(vv[j], hb, lb);
        (&h.x)[j] = (unsigned short)hb;
        (&l.x)[j] = (unsigned short)lb;
    }
    ((ushort4*)hi)[i] = h;
    ((ushort4*)lo)[i] = l;
}

// batch split+transpose of all weights: src [K][N] -> hi/lo [N][K]
struct WEnt { const float* src; unsigned short* hi; unsigned short* lo; int K; int N; };
struct WArr { WEnt e[15]; };

__global__ void split_weights(WArr a)
{
    WEnt w = a.e[blockIdx.y];
    int id = blockIdx.x * 256 + threadIdx.x;
    if (id >= w.K * w.N) return;
    int k = id / w.N, n = id - k * w.N;
    unsigned hb, lb;
    split1(w.src[id], hb, lb);
    w.hi[(size_t)n * w.K + k] = (unsigned short)hb;
    w.lo[(size_t)n * w.K + k] = (unsigned short)lb;
}

// ------------------------------------------------- MFMA split-bf16 GEMM
// C[M,N] = act(A@B + bias). A split row-major [M][K]; B split transposed [N][K]
// (padded to >=64 rows). Block = 4 waves = 64x64 tile; wave = 32x32 via
// mfma_f32_32x32x16_bf16 (frag layout verified in r5 attn).
__global__ __launch_bounds__(256) void gemm_mfma(
    const unsigned short* __restrict__ Ahi, const unsigned short* __restrict__ Alo,
    const unsigned short* __restrict__ Bhi, const unsigned short* __restrict__ Blo,
    const float* __restrict__ bias, float* __restrict__ C,
    unsigned short* __restrict__ Chi, unsigned short* __restrict__ Clo,
    int M, int N, int K, int act)
{
    const int lane = threadIdx.x & 63, wid = threadIdx.x >> 6;
    const int hb4 = lane >> 5, lq = lane & 31;
    const int row0 = blockIdx.y * 64 + (wid >> 1) * 32;
    const int col0 = blockIdx.x * 64 + (wid & 1) * 32;
    const size_t abase = (size_t)(row0 + lq) * K + hb4 * 8;
    const size_t bbase = (size_t)(col0 + lq) * K + hb4 * 8;
    f32x16 acc0, acc1;
#pragma unroll
    for (int r = 0; r < 16; ++r) { acc0[r] = 0.f; acc1[r] = 0.f; }
    for (int k0 = 0; k0 < K; k0 += 16) {
        bf16x8 a_h = *(const bf16x8*)(Ahi + abase + k0);
        bf16x8 a_l = *(const bf16x8*)(Alo + abase + k0);
        bf16x8 b_h = *(const bf16x8*)(Bhi + bbase + k0);
        bf16x8 b_l = *(const bf16x8*)(Blo + bbase + k0);
        acc0 = __builtin_amdgcn_mfma_f32_32x32x16_bf16(a_h, b_h, acc0, 0, 0, 0);
        acc1 = __builtin_amdgcn_mfma_f32_32x32x16_bf16(a_l, b_h, acc1, 0, 0, 0);
        acc1 = __builtin_amdgcn_mfma_f32_32x32x16_bf16(a_h, b_l, acc1, 0, 0, 0);
    }
    int col = col0 + lq;
    if (col >= N) return;
    float bs = bias ? bias[col] : 0.f;
#pragma unroll
    for (int r = 0; r < 16; ++r) {
        int row = row0 + (r & 3) + 8 * (r >> 2) + 4 * hb4;
        float v = acc0[r] + acc1[r] + bs;
        if (act) v = leaky(v);
        C[(size_t)row * N + col] = v;
        if (Chi) {
            unsigned hh, ll;
            split1(v, hh, ll);
            Chi[(size_t)row * N + col] = (unsigned short)hh;
            Clo[(size_t)row * N + col] = (unsigned short)ll;
        }
    }
}

// ------------------------------------------------- GAT attention scores
__global__ void sd_kernel(const float* __restrict__ hw, const float* __restrict__ a_s,
                          const float* __restrict__ a_d, float* __restrict__ sval,
                          float* __restrict__ dval, int Nn, int H)
{
    int i = blockIdx.x * blockDim.x + threadIdx.x;
    if (i >= Nn * H) return;
    int n = i / H, h = i - n * H;
    const float4* row = (const float4*)(hw + (size_t)n * H * 64 + h * 64);
    const float4* as4 = (const float4*)(a_s + h * 64);
    const float4* ad4 = (const float4*)(a_d + h * 64);
    float s = 0.f, d = 0.f;
#pragma unroll
    for (int c = 0; c < 16; ++c) {
        float4 x = row[c], a = as4[c], b = ad4[c];
        s += x.x * a.x + x.y * a.y + x.z * a.z + x.w * a.w;
        d += x.x * b.x + x.y * b.y + x.z * b.z + x.w * b.w;
    }
    sval[i] = s;
    dval[i] = d;
}

// ------------------------------------------------- CSR build (by dst)
__global__ void csr_count(const int* __restrict__ ei, int* __restrict__ cnt, int E) {
    int i = blockIdx.x * 256 + threadIdx.x;
    if (i < E) atomicAdd(&cnt[ei[E + i]], 1);
}

__global__ __launch_bounds__(256) void csr_scan(const int* __restrict__ cnt,
                                                int* __restrict__ rowptr,
                                                int* __restrict__ fill, int Nn)
{
    __shared__ int part[256];
    int t = threadIdx.x;
    int loc[32];
    int s = 0;
#pragma unroll
    for (int j = 0; j < 32; ++j) { loc[j] = s; s += cnt[t * 32 + j]; }
    part[t] = s;
    __syncthreads();
    for (int d = 1; d < 256; d <<= 1) {
        int v = (t >= d) ? part[t - d] : 0;
        __syncthreads();
        part[t] += v;
        __syncthreads();
    }
    int off = (t > 0) ? part[t - 1] : 0;
#pragma unroll
    for (int j = 0; j < 32; ++j) {
        int v = off + loc[j];
        rowptr[t * 32 + j] = v;
        fill[t * 32 + j] = v;
    }
    if (t == 255) rowptr[Nn] = part[255];
}

__global__ void csr_scatter(const int* __restrict__ ei, int* __restrict__ fill,
                            int* __restrict__ srcidx, int E) {
    int i = blockIdx.x * 256 + threadIdx.x;
    if (i < E) {
        int d = ei[E + i];
        int p = atomicAdd(&fill[d], 1);
        srcidx[p] = ei[i];
    }
}

// ------------------------------------------------- fused GAT gather
template <int H>
__global__ __launch_bounds__(256) void gat_gather(
    const int* __restrict__ rowptr, const int* __restrict__ srcidx,
    const float* __restrict__ hw, const float* __restrict__ sval,
    const float* __restrict__ dval, float* __restrict__ gout, int Nn)
{
    const int node = blockIdx.x * 4 + (threadIdx.x >> 6);
    const int lane = threadIdx.x & 63;
    const int beg = rowptr[node], end = rowptr[node + 1];
    const int C = H * 64;
    float dv[H], es[H], mh[H], lh[H], inv[H], acc[H];
#pragma unroll
    for (int h = 0; h < H; ++h) {
        dv[h] = dval[node * H + h];
        es[h] = leaky(sval[node * H + h] + dv[h]);
        mh[h] = -1e30f;
        lh[h] = 0.f;
    }
    for (int i = beg + lane; i < end; i += 64) {
        int s = srcidx[i];
#pragma unroll
        for (int h = 0; h < H; ++h)
            mh[h] = fmaxf(mh[h], leaky(sval[s * H + h] + dv[h]));
    }
#pragma unroll
    for (int h = 0; h < H; ++h) {
        float m = mh[h];
        for (int off = 32; off; off >>= 1) m = fmaxf(m, __shfl_xor(m, off));
        mh[h] = fmaxf(m, es[h]);
    }
    for (int i = beg + lane; i < end; i += 64) {
        int s = srcidx[i];
#pragma unroll
        for (int h = 0; h < H; ++h)
            lh[h] += __expf(leaky(sval[s * H + h] + dv[h]) - mh[h]);
    }
#pragma unroll
    for (int h = 0; h < H; ++h) {
        float l = lh[h];
        for (int off = 32; off; off >>= 1) l += __shfl_xor(l, off);
        l += __expf(es[h] - mh[h]);
        inv[h] = 1.f / (l + 1e-16f);
        acc[h] = __expf(es[h] - mh[h]) * inv[h] *
                 hw[(size_t)node * C + h * 64 + lane];
    }
    for (int i = beg; i < end; ++i) {
        int s = srcidx[i];
#pragma unroll
        for (int h = 0; h < H; ++h) {
            float e = leaky(sval[s * H + h] + dv[h]);
            float a = __expf(e - mh[h]) * inv[h];
            acc[h] += a * hw[(size_t)s * C + h * 64 + lane];
        }
    }
#pragma unroll
    for (int h = 0; h < H; ++h)
        gout[(size_t)node * C + h * 64 + lane] = acc[h];
}

// ------------------------------------------------- BatchNorm (batch stats)
__global__ void bn_partial(const float* __restrict__ gout, double* __restrict__ sums,
                           int Nn, int C)
{
    int t = threadIdx.x;
    int c = t % C, sub = t / C, nsub = blockDim.x / C;
    int rbase = blockIdx.x * 32;
    double s = 0.0, sq = 0.0;
    for (int r = rbase + sub; r < rbase + 32; r += nsub) {
        float x = gout[(size_t)r * C + c];
        s += x;
        sq += (double)x * x;
    }
    atomicAdd(&sums[c], s);
    atomicAdd(&sums[C + c], sq);
}

__global__ void bn_finalize(const double* __restrict__ sums, float* __restrict__ mu,
                            float* __restrict__ rstd, int Nn, int C)
{
    int c = threadIdx.x;
    if (c >= C) return;
    double m = sums[c] / Nn;
    double v = sums[C + c] / Nn - m * m;
    mu[c] = (float)m;
    rstd[c] = (float)(1.0 / sqrt(v + 1e-5));
}

// + fused hi/lo split of the activated output (feeds next layer's MFMA GEMM)
__global__ void bn_res_act(const float* __restrict__ gout, const float* __restrict__ res,
                           const float* __restrict__ mu, const float* __restrict__ rstd,
                           const float* __restrict__ g, const float* __restrict__ be,
                           float* __restrict__ out,
                           unsigned short* __restrict__ shi,
                           unsigned short* __restrict__ slo, int total, int C)
{
    int i = blockIdx.x * blockDim.x + threadIdx.x;
    if (i >= total) return;
    int c = i & (C - 1);
    float v = (gout[i] - mu[c]) * rstd[c] * g[c] + be[c] + res[i];
    v = leaky(v);
    out[i] = v;
    if (shi) {
        unsigned hb, lb;
        split1(v, hb, lb);
        shi[i] = (unsigned short)hb;
        slo[i] = (unsigned short)lb;
    }
}

__global__ void jk_max(const float* __restrict__ a, const float* __restrict__ b,
                       const float* __restrict__ c, float* __restrict__ z,
                       unsigned short* __restrict__ shi,
                       unsigned short* __restrict__ slo, int total)
{
    int i = blockIdx.x * blockDim.x + threadIdx.x;
    if (i >= total) return;
    float v = fmaxf(fmaxf(a[i], b[i]), c[i]);
    z[i] = v;
    unsigned hb, lb;
    split1(v, hb, lb);
    shi[i] = (unsigned short)hb;
    slo[i] = (unsigned short)lb;
}

// ------------------------------------------------- per-dim |k| max (both heads)
__global__ void kmax_kernel(const float* __restrict__ kg, unsigned* __restrict__ kmax,
                            int N)
{
    const int c = threadIdx.x & 63, g = threadIdx.x >> 6;
    const int rows = N / (gridDim.x * 4);
    const int r0 = (blockIdx.x * 4 + g) * rows;
    float m = 0.f;
    for (int r = r0; r < r0 + rows; ++r)
        m = fmaxf(m, fabsf(kg[(size_t)r * 64 + c]));
    atomicMax(&kmax[c], __float_as_uint(m));
}

// ------------------------------------------------- attn prep (as r5)
__global__ void qk_prep(const float* __restrict__ zq, const float* __restrict__ zk,
                        const unsigned* __restrict__ kmaxu,
                        __hip_bfloat16* __restrict__ Qb, __hip_bfloat16* __restrict__ Kb,
                        float* __restrict__ bound, int N)
{
    int idx = blockIdx.x * 256 + threadIdx.x;
    if (idx >= 2 * N) return;
    int h = idx / N, row = idx - h * N;
    const float scale = 0.17677669529663687f;
    const float* qp = zq + (size_t)row * 64 + h * 32;
    const float* kp = zk + (size_t)row * 64 + h * 32;
    float b = 0.f;
    unsigned qo[16], ko[16];
#pragma unroll
    for (int i = 0; i < 16; ++i) {
        float q0 = qp[2 * i] * scale, q1 = qp[2 * i + 1] * scale;
        float k0 = kp[2 * i], k1 = kp[2 * i + 1];
        b += fabsf(q0) * __uint_as_float(kmaxu[h * 32 + 2 * i]);
        b += fabsf(q1) * __uint_as_float(kmaxu[h * 32 + 2 * i + 1]);
        qo[i] = bf16u(q0) | (bf16u(q1) << 16);
        ko[i] = bf16u(k0) | (bf16u(k1) << 16);
    }
    uint4* qd = (uint4*)(Qb + (size_t)idx * 32);
    uint4* kd = (uint4*)(Kb + (size_t)idx * 32);
#pragma unroll
    for (int i = 0; i < 4; ++i) {
        qd[i] = make_uint4(qo[4 * i], qo[4 * i + 1], qo[4 * i + 2], qo[4 * i + 3]);
        kd[i] = make_uint4(ko[4 * i], ko[4 * i + 1], ko[4 * i + 2], ko[4 * i + 3]);
    }
    bound[idx] = b;
}

__global__ void v_prep(const float* __restrict__ zv, __hip_bfloat16* __restrict__ Vf,
                       int N)
{
    int idx = blockIdx.x * 256 + threadIdx.x;
    int total = 2 * (N >> 4) * 64;
    if (idx >= total) return;
    int lane = idx & 63;
    int g = (idx >> 6) % (N >> 4);
    int h = (idx >> 6) / (N >> 4);
    int kb = g * 16 + (lane >> 5) * 8;
    int d = (lane & 31) + h * 32;
    unsigned o[4];
#pragma unroll
    for (int i = 0; i < 4; ++i) {
        unsigned u0 = bf16u(zv[(size_t)(kb + 2 * i) * 64 + d]);
        unsigned u1 = bf16u(zv[(size_t)(kb + 2 * i + 1) * 64 + d]);
        o[i] = u0 | (u1 << 16);
    }
    *(uint4*)(Vf + (size_t)idx * 8) = make_uint4(o[0], o[1], o[2], o[3]);
}

// ------------------------------------------------- MFMA full self-attention (r5)
__global__ __launch_bounds__(256) void attn_mfma(
    const __hip_bfloat16* __restrict__ Qb, const __hip_bfloat16* __restrict__ Kb,
    const __hip_bfloat16* __restrict__ Vf, const float* __restrict__ bound,
    float* __restrict__ pl, __hip_bfloat16* __restrict__ pacc,
    int N, int nchunk, int chunksz)
{
    const int lane = threadIdx.x & 63;
    const int wid = threadIdx.x >> 6;
    const int hi = lane >> 5, lq = lane & 31;
    const int chunk = blockIdx.x;
    const int qtile = blockIdx.y * 4 + wid;
    const int head = qtile / (N >> 5);
    const int q0 = (qtile % (N >> 5)) * 32;
    const int kbase = chunk * chunksz;

    const size_t qrow = (size_t)head * N + q0 + lq;
    const bf16x8 qf0 = *(const bf16x8*)(Qb + qrow * 32 + hi * 8);
    const bf16x8 qf1 = *(const bf16x8*)(Qb + qrow * 32 + hi * 8 + 16);
    const float bnd = bound[qrow];

    f32x16 oacc;
#pragma unroll
    for (int r = 0; r < 16; ++r) oacc[r] = 0.f;
    float lsum = 0.f;

    for (int kt = kbase; kt < kbase + chunksz; kt += 32) {
        const size_t krow = (size_t)head * N + kt + lq;
        const bf16x8 kf0 = *(const bf16x8*)(Kb + krow * 32 + hi * 8);
        const bf16x8 kf1 = *(const bf16x8*)(Kb + krow * 32 + hi * 8 + 16);
        f32x16 s;
#pragma unroll
        for (int r = 0; r < 16; ++r) s[r] = 0.f;
        s = __builtin_amdgcn_mfma_f32_32x32x16_bf16(kf0, qf0, s, 0, 0, 0);
        s = __builtin_amdgcn_mfma_f32_32x32x16_bf16(kf1, qf1, s, 0, 0, 0);
        const __hip_bfloat16* vfb =
            Vf + (((size_t)head * (N >> 4) + (kt >> 4)) * 64 + lane) * 8;
        const bf16x8 vf0 = *(const bf16x8*)vfb;
        const bf16x8 vf1 = *(const bf16x8*)(vfb + 64 * 8);

        float p[16];
#pragma unroll
        for (int r = 0; r < 16; ++r) p[r] = __expf(s[r] - bnd);
        float ls = 0.f;
#pragma unroll
        for (int r = 0; r < 16; ++r) ls += p[r];
        lsum += ls;

        unsigned wpk[8];
#pragma unroll
        for (int i = 0; i < 8; ++i)
            wpk[i] = bf16u(p[2 * i]) | (bf16u(p[2 * i + 1]) << 16);
        unsigned wsx[8];
#pragma unroll
        for (int i = 0; i < 8; ++i) wsx[i] = (unsigned)__shfl_xor((int)wpk[i], 32);
        uint4v b1, b2;
        b1[0] = hi ? wsx[2] : wpk[0];
        b1[1] = hi ? wsx[3] : wpk[1];
        b1[2] = hi ? wpk[2] : wsx[0];
        b1[3] = hi ? wpk[3] : wsx[1];
        b2[0] = hi ? wsx[6] : wpk[4];
        b2[1] = hi ? wsx[7] : wpk[5];
        b2[2] = hi ? wpk[6] : wsx[4];
        b2[3] = hi ? wpk[7] : wsx[5];
        oacc = __builtin_amdgcn_mfma_f32_32x32x16_bf16(
            vf0, __builtin_bit_cast(bf16x8, b1), oacc, 0, 0, 0);
        oacc = __builtin_amdgcn_mfma_f32_32x32x16_bf16(
            vf1, __builtin_bit_cast(bf16x8, b2), oacc, 0, 0, 0);
    }
    lsum += __shfl_xor(lsum, 32);
    const size_t hr = (size_t)head * N + q0 + lq;
    if (hi == 0) pl[hr * nchunk + chunk] = lsum;
    __hip_bfloat16* pb = pacc + (hr * nchunk + chunk) * 32;
#pragma unroll
    for (int rg = 0; rg < 4; ++rg) {
        unsigned lo = bf16u(oacc[rg * 4 + 0]) | (bf16u(oacc[rg * 4 + 1]) << 16);
        unsigned hw2 = bf16u(oacc[rg * 4 + 2]) | (bf16u(oacc[rg * 4 + 3]) << 16);
        *(uint2*)(pb + rg * 8 + hi * 4) = make_uint2(lo, hw2);
    }
}

// combine + fused split of ao (feeds ow-GEMM)
__global__ void attn_combine(const float* __restrict__ pl,
                             const __hip_bfloat16* __restrict__ pacc,
                             float* __restrict__ og,
                             unsigned short* __restrict__ shi,
                             unsigned short* __restrict__ slo, int N, int nchunk)
{
    int i = blockIdx.x * blockDim.x + threadIdx.x;
    if (i >= 2 * N * 32) return;
    int hr = i >> 5, cc = i & 31;
    float l = 0.f, a = 0.f;
    for (int c = 0; c < nchunk; ++c) {
        l += pl[(size_t)hr * nchunk + c];
        a += __bfloat162float(pacc[((size_t)hr * nchunk + c) * 32 + cc]);
    }
    int head = hr / N, row = hr - head * N;
    float v = a / l;
    size_t oi = (size_t)row * 64 + head * 32 + cc;
    og[oi] = v;
    unsigned hb, lb;
    split1(v, hb, lb);
    shi[oi] = (unsigned short)hb;
    slo[oi] = (unsigned short)lb;
}

// ----------------------------------------------------------------- host
extern "C" void kernel_launch(void* const* d_in, const int* in_sizes, int n_in,
                              void* d_out, int out_size, void* d_ws, size_t ws_size,
                              hipStream_t stream)
{
    const float* x = (const float*)d_in[0];
    const int* ei = (const int*)d_in[1];
    const float* w[3]   = {(const float*)d_in[2], (const float*)d_in[6],  (const float*)d_in[10]};
    const float* as_[3] = {(const float*)d_in[3], (const float*)d_in[7],  (const float*)d_in[11]};
    const float* ad_[3] = {(const float*)d_in[4], (const float*)d_in[8],  (const float*)d_in[12]};
    const float* rw[3]  = {(const float*)d_in[5], (const float*)d_in[9],  (const float*)d_in[13]};
    const float* p0 = (const float*)d_in[14];
    const float* p1 = (const float*)d_in[15];
    const float* qw = (const float*)d_in[16];
    const float* kw = (const float*)d_in[17];
    const float* vw = (const float*)d_in[18];
    const float* ow = (const float*)d_in[19];
    const float* m1w = (const float*)d_in[20];
    const float* m2w = (const float*)d_in[21];
    const float* m3w = (const float*)d_in[22];
    const float* g_[3]  = {(const float*)d_in[23], (const float*)d_in[24], (const float*)d_in[25]};
    const float* be_[3] = {(const float*)d_in[26], (const float*)d_in[27], (const float*)d_in[28]};
    // d_in[29..31] = b0,b1,b2: constant shift cancels inside BatchNorm -> unused
    const float* qb  = (const float*)d_in[32];
    const float* kb  = (const float*)d_in[33];
    const float* vb  = (const float*)d_in[34];
    const float* ob  = (const float*)d_in[35];
    const float* m1b = (const float*)d_in[36];
    const float* m2b = (const float*)d_in[37];
    const float* m3b = (const float*)d_in[38];

    const int N = in_sizes[0] / 64; // 8192
    const int E = in_sizes[1] / 2;  // 262144

    float* ws = (float*)d_ws;
    size_t off = 0;
    auto alloc = [&](size_t n) {
        float* p = ws + off;
        off += (n + 255) & ~(size_t)255;
        return p;
    };
    float* hw   = alloc((size_t)N * 256);
    float* res  = alloc((size_t)N * 256);
    float* gout = alloc((size_t)N * 256);
    float* h0   = alloc((size_t)N * 256);
    float* h1   = alloc((size_t)N * 256);
    float* h2   = alloc((size_t)N * 64);
    float* sval = alloc((size_t)N * 4);
    float* dval = alloc((size_t)N * 4);
    double* bnsum = (double*)alloc(1024);
    float* mu   = alloc(256);
    float* rstd = alloc(256);
    int* cnt    = (int*)alloc(N);
    int* rowptr = (int*)alloc(N + 256);
    int* fill   = (int*)alloc(N);
    int* srcidx = (int*)alloc(E);
    unsigned* kmaxu = (unsigned*)alloc(64);
    // split scratch: sA pair (up to N x 256), sB pair (up to N x 64)
    unsigned short* sAhi = (unsigned short*)alloc((size_t)N * 128);
    unsigned short* sAlo = (unsigned short*)alloc((size_t)N * 128);
    unsigned short* sBhi = (unsigned short*)alloc((size_t)N * 32);
    unsigned short* sBlo = (unsigned short*)alloc((size_t)N * 32);
    // weight splits (transposed [N][K], N padded to >=64)
    const float* wsrc[15] = {w[0], rw[0], w[1], rw[1], w[2], rw[2], p0, p1,
                             qw, kw, vw, ow, m1w, m2w, m3w};
    const int wK[15] = {64, 64, 256, 256, 256, 256, 256, 256, 64, 64, 64, 64, 64, 64, 32};
    const int wN[15] = {256, 256, 256, 256, 64, 64, 64, 64, 64, 64, 64, 64, 64, 32, 10};
    unsigned short *whi[15], *wlo[15];
    for (int i = 0; i < 15; ++i) {
        int padN = wN[i] < 64 ? 64 : wN[i];
        whi[i] = (unsigned short*)alloc((size_t)padN * wK[i] / 2);
        wlo[i] = (unsigned short*)alloc((size_t)padN * wK[i] / 2);
    }
    // post-GAT aliases (hw dead after layer 3)
    float* zq = hw;
    float* zk = hw + (size_t)N * 64;
    float* zv = hw + 2 * (size_t)N * 64;
    float* ao = hw + 3 * (size_t)N * 64;
    float* z  = gout;
    float* tA = res;
    float* tB = res + (size_t)N * 64;
    float* tC = res + 2 * (size_t)N * 64;
    // attn buffers: Qb/Kb/Vf/bound in h0 (dead after JK); pacc=res (dead); pl=h2
    const int NCHUNK = 8;
    __hip_bfloat16* Qb = (__hip_bfloat16*)h0;
    __hip_bfloat16* Kb = Qb + (size_t)2 * N * 32;
    __hip_bfloat16* Vf = Kb + (size_t)2 * N * 32;
    float* boundArr = (float*)(Vf + (size_t)2 * N * 32);
    __hip_bfloat16* pacc = (__hip_bfloat16*)res;
    float* pl = h2;

    auto gemmM = [&](const unsigned short* Ahi_, const unsigned short* Alo_, int widx,
                     const float* bias, float* C, unsigned short* Chi,
                     unsigned short* Clo, int M, int Nc, int K, int act) {
        dim3 grid((Nc + 63) / 64, M / 64);
        gemm_mfma<<<grid, 256, 0, stream>>>(Ahi_, Alo_, whi[widx], wlo[widx],
                                            bias, C, Chi, Clo, M, Nc, K, act);
    };

    // weights: batch split+transpose (one launch)
    {
        WArr wa;
        for (int i = 0; i < 15; ++i)
            wa.e[i] = WEnt{wsrc[i], whi[i], wlo[i], wK[i], wN[i]};
        split_weights<<<dim3(256, 15), 256, 0, stream>>>(wa);
    }

    // CSR build (edge_index constant across layers)
    hipMemsetAsync(cnt, 0, (size_t)N * 4, stream);
    csr_count<<<(E + 255) / 256, 256, 0, stream>>>(ei, cnt, E);
    csr_scan<<<1, 256, 0, stream>>>(cnt, rowptr, fill, N);
    csr_scatter<<<(E + 255) / 256, 256, 0, stream>>>(ei, fill, srcidx, E);

    // x -> sA split
    split_rows<<<(N * 64 / 4 + 255) / 256, 256, 0, stream>>>(x, sAhi, sAlo, N * 64 / 4);

    float* houts[3] = {h0, h1, h2};
    int heads[3] = {4, 4, 1};
    int Kin = 64;

    for (int l = 0; l < 3; ++l) {
        int H = heads[l], C = H * 64;
        gemmM(sAhi, sAlo, 2 * l, nullptr, hw, nullptr, nullptr, N, C, Kin, 0);
        gemmM(sAhi, sAlo, 2 * l + 1, nullptr, res, nullptr, nullptr, N, C, Kin, 0);
        sd_kernel<<<(N * H + 255) / 256, 256, 0, stream>>>(hw, as_[l], ad_[l], sval, dval, N, H);
        if (H == 4)
            gat_gather<4><<<N / 4, 256, 0, stream>>>(rowptr, srcidx, hw, sval, dval, gout, N);
        else
            gat_gather<1><<<N / 4, 256, 0, stream>>>(rowptr, srcidx, hw, sval, dval, gout, N);
        hipMemsetAsync(bnsum, 0, (size_t)2 * C * 8, stream);
        bn_partial<<<N / 32, 256, 0, stream>>>(gout, bnsum, N, C);
        bn_finalize<<<1, 256, 0, stream>>>(bnsum, mu, rstd, N, C);
        // fuse split of h_l into sA for next layer (l<2); h2 needs no split
        bn_res_act<<<((size_t)N * C) / 256, 256, 0, stream>>>(
            gout, res, mu, rstd, g_[l], be_[l], houts[l],
            l < 2 ? sAhi : nullptr, l < 2 ? sAlo : nullptr, N * C, C);
        Kin = C;
    }

    // JumpingKnowledge: p1 first (sA still holds h1 split), then re-split h0
    gemmM(sAhi, sAlo, 7, nullptr, tB, nullptr, nullptr, N, 64, 256, 0);
    split_rows<<<(N * 256 / 4 + 255) / 256, 256, 0, stream>>>(h0, sAhi, sAlo, N * 256 / 4);
    gemmM(sAhi, sAlo, 6, nullptr, tA, nullptr, nullptr, N, 64, 256, 0);
    jk_max<<<((size_t)N * 64) / 256, 256, 0, stream>>>(tA, tB, h2, z, sAhi, sAlo, N * 64);

    // qkv (from z split in sA)
    gemmM(sAhi, sAlo, 8, qb, zq, nullptr, nullptr, N, 64, 64, 0);
    gemmM(sAhi, sAlo, 9, kb, zk, nullptr, nullptr, N, 64, 64, 0);
    gemmM(sAhi, sAlo, 10, vb, zv, nullptr, nullptr, N, 64, 64, 0);

    // attention (bf16 MFMA flash, fixed-shift softmax)
    hipMemsetAsync(kmaxu, 0, 64 * 4, stream);
    kmax_kernel<<<32, 256, 0, stream>>>(zk, kmaxu, N);
    qk_prep<<<(2 * N + 255) / 256, 256, 0, stream>>>(zq, zk, kmaxu, Qb, Kb, boundArr, N);
    v_prep<<<(2 * (N >> 4) * 64 + 255) / 256, 256, 0, stream>>>(zv, Vf, N);
    attn_mfma<<<dim3(NCHUNK, (2 * N / 32) / 4), 256, 0, stream>>>(
        Qb, Kb, Vf, boundArr, pl, pacc, N, NCHUNK, N / NCHUNK);
    attn_combine<<<(2 * N * 32 + 255) / 256, 256, 0, stream>>>(
        pl, pacc, ao, sAhi, sAlo, N, NCHUNK);

    // ow + MLP head (ping-pong sA/sB splits via gemm epilogue fusion)
    gemmM(sAhi, sAlo, 11, ob, tA, sBhi, sBlo, N, 64, 64, 0);
    gemmM(sBhi, sBlo, 12, m1b, tB, sAhi, sAlo, N, 64, 64, 1);
    gemmM(sAhi, sAlo, 13, m2b, tC, sBhi, sBlo, N, 32, 64, 1);
    gemmM(sBhi, sBlo, 14, m3b, (float*)d_out, nullptr, nullptr, N, 10, 32, 0);
}

// Round 8
// 408.516 us; speedup vs baseline: 1.9206x; 1.1216x over previous
//
#include <hip/hip_runtime.h>
#include <hip/hip_bf16.h>

// NeuronGAT forward. Round 7:
//  - gat_gather: single-pass (fixed-bound softmax via global per-head sval max,
//    fused into sd_kernel). 3 edge passes -> 1.
//  - fused GEMMs: w|r per layer ([N][2C] out), q|k|v ([N][192] out, biases
//    folded into attn preps). Dead fp32 writes dropped; one coalesced memset.
//  - attn_mfma + split-bf16 gemm_mfma unchanged (verified r5/r6).

#define NEG 0.2f

__device__ __forceinline__ float leaky(float v) { return v > 0.f ? v : NEG * v; }

__device__ __forceinline__ unsigned bf16u(float x) {
    unsigned u = __float_as_uint(x);
    u += 0x7FFFu + ((u >> 16) & 1u);
    return u >> 16;
}
// monotonic float<->uint for atomicMax on floats
__device__ __forceinline__ unsigned fmap(float f) {
    unsigned u = __float_as_uint(f);
    return (u & 0x80000000u) ? ~u : (u | 0x80000000u);
}
__device__ __forceinline__ float funmap(unsigned u) {
    unsigned b = (u & 0x80000000u) ? (u & 0x7FFFFFFFu) : ~u;
    return __uint_as_float(b);
}

typedef __attribute__((ext_vector_type(8))) short bf16x8;
typedef __attribute__((ext_vector_type(16))) float f32x16;
typedef __attribute__((ext_vector_type(4))) unsigned uint4v;

__device__ __forceinline__ void split1(float v, unsigned& hb, unsigned& lb) {
    hb = bf16u(v);
    float hf = __uint_as_float(hb << 16);
    lb = bf16u(v - hf);
}

__global__ void split_rows(const float* __restrict__ in,
                           unsigned short* __restrict__ hi,
                           unsigned short* __restrict__ lo, int total4)
{
    int i = blockIdx.x * 256 + threadIdx.x;
    if (i >= total4) return;
    float4 v = ((const float4*)in)[i];
    float vv[4] = {v.x, v.y, v.z, v.w};
    ushort4 h, l;
#pragma unroll
    for (int j = 0; j < 4; ++j) {
        unsigned hb, lb;
        split1(vv[j], hb, lb);
        (&h.x)[j] = (unsigned short)hb;
        (&l.x)[j] = (unsigned short)lb;
    }
    ((ushort4*)hi)[i] = h;
    ((ushort4*)lo)[i] = l;
}

struct WEnt { const float* src; unsigned short* hi; unsigned short* lo; int K; int N; };
struct WArr { WEnt e[15]; };

__global__ void split_weights(WArr a)
{
    WEnt w = a.e[blockIdx.y];
    int id = blockIdx.x * 256 + threadIdx.x;
    if (id >= w.K * w.N) return;
    int k = id / w.N, n = id - k * w.N;
    unsigned hb, lb;
    split1(w.src[id], hb, lb);
    w.hi[(size_t)n * w.K + k] = (unsigned short)hb;
    w.lo[(size_t)n * w.K + k] = (unsigned short)lb;
}

// ------------------------------------------------- MFMA split-bf16 GEMM (r6)
__global__ __launch_bounds__(256) void gemm_mfma(
    const unsigned short* __restrict__ Ahi, const unsigned short* __restrict__ Alo,
    const unsigned short* __restrict__ Bhi, const unsigned short* __restrict__ Blo,
    const float* __restrict__ bias, float* __restrict__ C,
    unsigned short* __restrict__ Chi, unsigned short* __restrict__ Clo,
    int M, int N, int K, int act)
{
    const int lane = threadIdx.x & 63, wid = threadIdx.x >> 6;
    const int hb4 = lane >> 5, lq = lane & 31;
    const int row0 = blockIdx.y * 64 + (wid >> 1) * 32;
    const int col0 = blockIdx.x * 64 + (wid & 1) * 32;
    const size_t abase = (size_t)(row0 + lq) * K + hb4 * 8;
    const size_t bbase = (size_t)(col0 + lq) * K + hb4 * 8;
    f32x16 acc0, acc1;
#pragma unroll
    for (int r = 0; r < 16; ++r) { acc0[r] = 0.f; acc1[r] = 0.f; }
    for (int k0 = 0; k0 < K; k0 += 16) {
        bf16x8 a_h = *(const bf16x8*)(Ahi + abase + k0);
        bf16x8 a_l = *(const bf16x8*)(Alo + abase + k0);
        bf16x8 b_h = *(const bf16x8*)(Bhi + bbase + k0);
        bf16x8 b_l = *(const bf16x8*)(Blo + bbase + k0);
        acc0 = __builtin_amdgcn_mfma_f32_32x32x16_bf16(a_h, b_h, acc0, 0, 0, 0);
        acc1 = __builtin_amdgcn_mfma_f32_32x32x16_bf16(a_l, b_h, acc1, 0, 0, 0);
        acc1 = __builtin_amdgcn_mfma_f32_32x32x16_bf16(a_h, b_l, acc1, 0, 0, 0);
    }
    int col = col0 + lq;
    if (col >= N) return;
    float bs = bias ? bias[col] : 0.f;
#pragma unroll
    for (int r = 0; r < 16; ++r) {
        int row = row0 + (r & 3) + 8 * (r >> 2) + 4 * hb4;
        float v = acc0[r] + acc1[r] + bs;
        if (act) v = leaky(v);
        C[(size_t)row * N + col] = v;
        if (Chi) {
            unsigned hh, ll;
            split1(v, hh, ll);
            Chi[(size_t)row * N + col] = (unsigned short)hh;
            Clo[(size_t)row * N + col] = (unsigned short)ll;
        }
    }
}

// ------------------------------------------------- GAT scores + global head max
template <int H>
__global__ __launch_bounds__(256) void sd_kernel(
    const float* __restrict__ hwres, int S,
    const float* __restrict__ a_s, const float* __restrict__ a_d,
    float* __restrict__ sval, float* __restrict__ dval,
    unsigned* __restrict__ svmax, int Nn)
{
    int i = blockIdx.x * 256 + threadIdx.x;   // Nn*H is a multiple of 256
    int n = i / H, h = i & (H - 1);
    const float4* row = (const float4*)(hwres + (size_t)n * S + h * 64);
    const float4* as4 = (const float4*)(a_s + h * 64);
    const float4* ad4 = (const float4*)(a_d + h * 64);
    float s = 0.f, d = 0.f;
#pragma unroll
    for (int c = 0; c < 16; ++c) {
        float4 x = row[c], a = as4[c], b = ad4[c];
        s += x.x * a.x + x.y * a.y + x.z * a.z + x.w * a.w;
        d += x.x * b.x + x.y * b.y + x.z * b.z + x.w * b.w;
    }
    sval[i] = s;
    dval[i] = d;
    // per-head global max of sval (wave-reduce within head class, then atomic)
    float m = s;
#pragma unroll
    for (int off = H; off < 64; off <<= 1) m = fmaxf(m, __shfl_xor(m, off));
    if ((threadIdx.x & 63) < H) atomicMax(&svmax[h], fmap(m));
}

// ------------------------------------------------- CSR build (by dst)
__global__ void csr_count(const int* __restrict__ ei, int* __restrict__ cnt, int E) {
    int i = blockIdx.x * 256 + threadIdx.x;
    if (i < E) atomicAdd(&cnt[ei[E + i]], 1);
}

__global__ __launch_bounds__(256) void csr_scan(const int* __restrict__ cnt,
                                                int* __restrict__ rowptr,
                                                int* __restrict__ fill, int Nn)
{
    __shared__ int part[256];
    int t = threadIdx.x;
    int loc[32];
    int s = 0;
#pragma unroll
    for (int j = 0; j < 32; ++j) { loc[j] = s; s += cnt[t * 32 + j]; }
    part[t] = s;
    __syncthreads();
    for (int d = 1; d < 256; d <<= 1) {
        int v = (t >= d) ? part[t - d] : 0;
        __syncthreads();
        part[t] += v;
        __syncthreads();
    }
    int off = (t > 0) ? part[t - 1] : 0;
#pragma unroll
    for (int j = 0; j < 32; ++j) {
        int v = off + loc[j];
        rowptr[t * 32 + j] = v;
        fill[t * 32 + j] = v;
    }
    if (t == 255) rowptr[Nn] = part[255];
}

__global__ void csr_scatter(const int* __restrict__ ei, int* __restrict__ fill,
                            int* __restrict__ srcidx, int E) {
    int i = blockIdx.x * 256 + threadIdx.x;
    if (i < E) {
        int d = ei[E + i];
        int p = atomicAdd(&fill[d], 1);
        srcidx[p] = ei[i];
    }
}

// ------------------------------------------------- single-pass GAT gather
// bound B_h = leaky(global_max(sval)+dv) >= every in-edge score (leaky monotone)
// => p = exp(e - B) <= 1, softmax shift cancels in acc/l ratio. One edge pass.
template <int H>
__global__ __launch_bounds__(256) void gat_gather(
    const int* __restrict__ rowptr, const int* __restrict__ srcidx,
    const float* __restrict__ hwres, int S,
    const float* __restrict__ sval, const float* __restrict__ dval,
    const unsigned* __restrict__ svmax, float* __restrict__ gout, int Nn)
{
    const int node = blockIdx.x * 4 + (threadIdx.x >> 6);
    const int lane = threadIdx.x & 63;
    const int beg = rowptr[node], end = rowptr[node + 1];
    const int C = H * 64;
    float dv[H], B[H], acc[H], l[H];
    if constexpr (H == 4) {
        float4 t = *(const float4*)(dval + node * 4);
        dv[0] = t.x; dv[1] = t.y; dv[2] = t.z; dv[3] = t.w;
    } else {
        dv[0] = dval[node];
    }
#pragma unroll
    for (int h = 0; h < H; ++h) {
        B[h] = leaky(funmap(svmax[h]) + dv[h]);
        float es;
        if constexpr (H == 4) es = sval[node * 4 + h]; else es = sval[node];
        float p = __expf(leaky(es + dv[h]) - B[h]);   // self-loop
        l[h] = p;
        acc[h] = p * hwres[(size_t)node * S + h * 64 + lane];
    }
    int i = beg;
    for (; i + 2 <= end; i += 2) {
        int s0 = srcidx[i], s1 = srcidx[i + 1];
        float se0[H], se1[H];
        if constexpr (H == 4) {
            float4 t0 = *(const float4*)(sval + s0 * 4);
            float4 t1 = *(const float4*)(sval + s1 * 4);
            se0[0] = t0.x; se0[1] = t0.y; se0[2] = t0.z; se0[3] = t0.w;
            se1[0] = t1.x; se1[1] = t1.y; se1[2] = t1.z; se1[3] = t1.w;
        } else { se0[0] = sval[s0]; se1[0] = sval[s1]; }
        const float* r0 = hwres + (size_t)s0 * S + lane;
        const float* r1 = hwres + (size_t)s1 * S + lane;
#pragma unroll
        for (int h = 0; h < H; ++h) {
            float p0 = __expf(leaky(se0[h] + dv[h]) - B[h]);
            float p1 = __expf(leaky(se1[h] + dv[h]) - B[h]);
            l[h] += p0 + p1;
            acc[h] += p0 * r0[h * 64] + p1 * r1[h * 64];
        }
    }
    for (; i < end; ++i) {
        int s0 = srcidx[i];
        float se0[H];
        if constexpr (H == 4) {
            float4 t0 = *(const float4*)(sval + s0 * 4);
            se0[0] = t0.x; se0[1] = t0.y; se0[2] = t0.z; se0[3] = t0.w;
        } else { se0[0] = sval[s0]; }
        const float* r0 = hwres + (size_t)s0 * S + lane;
#pragma unroll
        for (int h = 0; h < H; ++h) {
            float p0 = __expf(leaky(se0[h] + dv[h]) - B[h]);
            l[h] += p0;
            acc[h] += p0 * r0[h * 64];
        }
    }
#pragma unroll
    for (int h = 0; h < H; ++h)
        gout[(size_t)node * C + h * 64 + lane] = acc[h] / l[h];
}

// ------------------------------------------------- BatchNorm (batch stats)
__global__ void bn_partial(const float* __restrict__ gout, double* __restrict__ sums,
                           int Nn, int C)
{
    int t = threadIdx.x;
    int c = t % C, sub = t / C, nsub = blockDim.x / C;
    int rbase = blockIdx.x * 32;
    double s = 0.0, sq = 0.0;
    for (int r = rbase + sub; r < rbase + 32; r += nsub) {
        float x = gout[(size_t)r * C + c];
        s += x;
        sq += (double)x * x;
    }
    atomicAdd(&sums[c], s);
    atomicAdd(&sums[C + c], sq);
}

__global__ void bn_finalize(const double* __restrict__ sums, float* __restrict__ mu,
                            float* __restrict__ rstd, int Nn, int C)
{
    int c = threadIdx.x;
    if (c >= C) return;
    double m = sums[c] / Nn;
    double v = sums[C + c] / Nn - m * m;
    mu[c] = (float)m;
    rstd[c] = (float)(1.0 / sqrt(v + 1e-5));
}

// res read from hwres[row*S + C + c]; optional fp32 out; optional split out
__global__ void bn_res_act(const float* __restrict__ gout,
                           const float* __restrict__ hwres, int S, int logC,
                           const float* __restrict__ mu, const float* __restrict__ rstd,
                           const float* __restrict__ g, const float* __restrict__ be,
                           float* __restrict__ outp,
                           unsigned short* __restrict__ shi,
                           unsigned short* __restrict__ slo, int total)
{
    int i = blockIdx.x * blockDim.x + threadIdx.x;
    if (i >= total) return;
    int C = 1 << logC;
    int c = i & (C - 1), row = i >> logC;
    float v = (gout[i] - mu[c]) * rstd[c] * g[c] + be[c]
              + hwres[(size_t)row * S + C + c];
    v = leaky(v);
    if (outp) outp[i] = v;
    if (shi) {
        unsigned hb, lb;
        split1(v, hb, lb);
        shi[i] = (unsigned short)hb;
        slo[i] = (unsigned short)lb;
    }
}

__global__ void jk_max(const float* __restrict__ a, const float* __restrict__ b,
                       const float* __restrict__ c,
                       unsigned short* __restrict__ shi,
                       unsigned short* __restrict__ slo, int total)
{
    int i = blockIdx.x * blockDim.x + threadIdx.x;
    if (i >= total) return;
    float v = fmaxf(fmaxf(a[i], b[i]), c[i]);
    unsigned hb, lb;
    split1(v, hb, lb);
    shi[i] = (unsigned short)hb;
    slo[i] = (unsigned short)lb;
}

// ------------------------------------------------- per-dim |k| max (biased k)
__global__ void kmax_kernel(const float* __restrict__ zqkv,
                            const float* __restrict__ kb,
                            unsigned* __restrict__ kmax, int N)
{
    const int c = threadIdx.x & 63, g = threadIdx.x >> 6;
    const int rows = N / (gridDim.x * 4);
    const int r0 = (blockIdx.x * 4 + g) * rows;
    float bc = kb[c];
    float m = 0.f;
    for (int r = r0; r < r0 + rows; ++r)
        m = fmaxf(m, fabsf(zqkv[(size_t)r * 192 + 64 + c] + bc));
    atomicMax(&kmax[c], __float_as_uint(m));
}

// ------------------------------------------------- attn prep (zqkv stride 192)
__global__ void qk_prep(const float* __restrict__ zqkv,
                        const float* __restrict__ qb, const float* __restrict__ kb,
                        const unsigned* __restrict__ kmaxu,
                        __hip_bfloat16* __restrict__ Qb, __hip_bfloat16* __restrict__ Kb,
                        float* __restrict__ bound, int N)
{
    int idx = blockIdx.x * 256 + threadIdx.x;
    if (idx >= 2 * N) return;
    int h = idx / N, row = idx - h * N;
    const float scale = 0.17677669529663687f;
    const float* qp = zqkv + (size_t)row * 192 + h * 32;
    const float* kp = zqkv + (size_t)row * 192 + 64 + h * 32;
    float b = 0.f;
    unsigned qo[16], ko[16];
#pragma unroll
    for (int i = 0; i < 16; ++i) {
        float q0 = (qp[2 * i] + qb[h * 32 + 2 * i]) * scale;
        float q1 = (qp[2 * i + 1] + qb[h * 32 + 2 * i + 1]) * scale;
        float k0 = kp[2 * i] + kb[h * 32 + 2 * i];
        float k1 = kp[2 * i + 1] + kb[h * 32 + 2 * i + 1];
        b += fabsf(q0) * __uint_as_float(kmaxu[h * 32 + 2 * i]);
        b += fabsf(q1) * __uint_as_float(kmaxu[h * 32 + 2 * i + 1]);
        qo[i] = bf16u(q0) | (bf16u(q1) << 16);
        ko[i] = bf16u(k0) | (bf16u(k1) << 16);
    }
    uint4* qd = (uint4*)(Qb + (size_t)idx * 32);
    uint4* kd = (uint4*)(Kb + (size_t)idx * 32);
#pragma unroll
    for (int i = 0; i < 4; ++i) {
        qd[i] = make_uint4(qo[4 * i], qo[4 * i + 1], qo[4 * i + 2], qo[4 * i + 3]);
        kd[i] = make_uint4(ko[4 * i], ko[4 * i + 1], ko[4 * i + 2], ko[4 * i + 3]);
    }
    bound[idx] = b;
}

__global__ void v_prep(const float* __restrict__ zqkv, const float* __restrict__ vb,
                       __hip_bfloat16* __restrict__ Vf, int N)
{
    int idx = blockIdx.x * 256 + threadIdx.x;
    int total = 2 * (N >> 4) * 64;
    if (idx >= total) return;
    int lane = idx & 63;
    int g = (idx >> 6) % (N >> 4);
    int h = (idx >> 6) / (N >> 4);
    int kb_ = g * 16 + (lane >> 5) * 8;
    int d = (lane & 31) + h * 32;
    float bd = vb[d];
    unsigned o[4];
#pragma unroll
    for (int i = 0; i < 4; ++i) {
        unsigned u0 = bf16u(zqkv[(size_t)(kb_ + 2 * i) * 192 + 128 + d] + bd);
        unsigned u1 = bf16u(zqkv[(size_t)(kb_ + 2 * i + 1) * 192 + 128 + d] + bd);
        o[i] = u0 | (u1 << 16);
    }
    *(uint4*)(Vf + (size_t)idx * 8) = make_uint4(o[0], o[1], o[2], o[3]);
}

// ------------------------------------------------- MFMA self-attention (r5)
__global__ __launch_bounds__(256) void attn_mfma(
    const __hip_bfloat16* __restrict__ Qb, const __hip_bfloat16* __restrict__ Kb,
    const __hip_bfloat16* __restrict__ Vf, const float* __restrict__ bound,
    float* __restrict__ pl, __hip_bfloat16* __restrict__ pacc,
    int N, int nchunk, int chunksz)
{
    const int lane = threadIdx.x & 63;
    const int wid = threadIdx.x >> 6;
    const int hi = lane >> 5, lq = lane & 31;
    const int chunk = blockIdx.x;
    const int qtile = blockIdx.y * 4 + wid;
    const int head = qtile / (N >> 5);
    const int q0 = (qtile % (N >> 5)) * 32;
    const int kbase = chunk * chunksz;

    const size_t qrow = (size_t)head * N + q0 + lq;
    const bf16x8 qf0 = *(const bf16x8*)(Qb + qrow * 32 + hi * 8);
    const bf16x8 qf1 = *(const bf16x8*)(Qb + qrow * 32 + hi * 8 + 16);
    const float bnd = bound[qrow];

    f32x16 oacc;
#pragma unroll
    for (int r = 0; r < 16; ++r) oacc[r] = 0.f;
    float lsum = 0.f;

    for (int kt = kbase; kt < kbase + chunksz; kt += 32) {
        const size_t krow = (size_t)head * N + kt + lq;
        const bf16x8 kf0 = *(const bf16x8*)(Kb + krow * 32 + hi * 8);
        const bf16x8 kf1 = *(const bf16x8*)(Kb + krow * 32 + hi * 8 + 16);
        f32x16 s;
#pragma unroll
        for (int r = 0; r < 16; ++r) s[r] = 0.f;
        s = __builtin_amdgcn_mfma_f32_32x32x16_bf16(kf0, qf0, s, 0, 0, 0);
        s = __builtin_amdgcn_mfma_f32_32x32x16_bf16(kf1, qf1, s, 0, 0, 0);
        const __hip_bfloat16* vfb =
            Vf + (((size_t)head * (N >> 4) + (kt >> 4)) * 64 + lane) * 8;
        const bf16x8 vf0 = *(const bf16x8*)vfb;
        const bf16x8 vf1 = *(const bf16x8*)(vfb + 64 * 8);

        float p[16];
#pragma unroll
        for (int r = 0; r < 16; ++r) p[r] = __expf(s[r] - bnd);
        float ls = 0.f;
#pragma unroll
        for (int r = 0; r < 16; ++r) ls += p[r];
        lsum += ls;

        unsigned wpk[8];
#pragma unroll
        for (int i = 0; i < 8; ++i)
            wpk[i] = bf16u(p[2 * i]) | (bf16u(p[2 * i + 1]) << 16);
        unsigned wsx[8];
#pragma unroll
        for (int i = 0; i < 8; ++i) wsx[i] = (unsigned)__shfl_xor((int)wpk[i], 32);
        uint4v b1, b2;
        b1[0] = hi ? wsx[2] : wpk[0];
        b1[1] = hi ? wsx[3] : wpk[1];
        b1[2] = hi ? wpk[2] : wsx[0];
        b1[3] = hi ? wpk[3] : wsx[1];
        b2[0] = hi ? wsx[6] : wpk[4];
        b2[1] = hi ? wsx[7] : wpk[5];
        b2[2] = hi ? wpk[6] : wsx[4];
        b2[3] = hi ? wpk[7] : wsx[5];
        oacc = __builtin_amdgcn_mfma_f32_32x32x16_bf16(
            vf0, __builtin_bit_cast(bf16x8, b1), oacc, 0, 0, 0);
        oacc = __builtin_amdgcn_mfma_f32_32x32x16_bf16(
            vf1, __builtin_bit_cast(bf16x8, b2), oacc, 0, 0, 0);
    }
    lsum += __shfl_xor(lsum, 32);
    const size_t hr = (size_t)head * N + q0 + lq;
    if (hi == 0) pl[hr * nchunk + chunk] = lsum;
    __hip_bfloat16* pb = pacc + (hr * nchunk + chunk) * 32;
#pragma unroll
    for (int rg = 0; rg < 4; ++rg) {
        unsigned lo = bf16u(oacc[rg * 4 + 0]) | (bf16u(oacc[rg * 4 + 1]) << 16);
        unsigned hw2 = bf16u(oacc[rg * 4 + 2]) | (bf16u(oacc[rg * 4 + 3]) << 16);
        *(uint2*)(pb + rg * 8 + hi * 4) = make_uint2(lo, hw2);
    }
}

// combine -> split only (fp32 ao never consumed)
__global__ void attn_combine(const float* __restrict__ pl,
                             const __hip_bfloat16* __restrict__ pacc,
                             unsigned short* __restrict__ shi,
                             unsigned short* __restrict__ slo, int N, int nchunk)
{
    int i = blockIdx.x * blockDim.x + threadIdx.x;
    if (i >= 2 * N * 32) return;
    int hr = i >> 5, cc = i & 31;
    float l = 0.f, a = 0.f;
    for (int c = 0; c < nchunk; ++c) {
        l += pl[(size_t)hr * nchunk + c];
        a += __bfloat162float(pacc[((size_t)hr * nchunk + c) * 32 + cc]);
    }
    int head = hr / N, row = hr - head * N;
    float v = a / l;
    size_t oi = (size_t)row * 64 + head * 32 + cc;
    unsigned hb, lb;
    split1(v, hb, lb);
    shi[oi] = (unsigned short)hb;
    slo[oi] = (unsigned short)lb;
}

// ----------------------------------------------------------------- host
extern "C" void kernel_launch(void* const* d_in, const int* in_sizes, int n_in,
                              void* d_out, int out_size, void* d_ws, size_t ws_size,
                              hipStream_t stream)
{
    const float* x = (const float*)d_in[0];
    const int* ei = (const int*)d_in[1];
    const float* w[3]   = {(const float*)d_in[2], (const float*)d_in[6],  (const float*)d_in[10]};
    const float* as_[3] = {(const float*)d_in[3], (const float*)d_in[7],  (const float*)d_in[11]};
    const float* ad_[3] = {(const float*)d_in[4], (const float*)d_in[8],  (const float*)d_in[12]};
    const float* rw[3]  = {(const float*)d_in[5], (const float*)d_in[9],  (const float*)d_in[13]};
    const float* p0 = (const float*)d_in[14];
    const float* p1 = (const float*)d_in[15];
    const float* qw = (const float*)d_in[16];
    const float* kw = (const float*)d_in[17];
    const float* vw = (const float*)d_in[18];
    const float* ow = (const float*)d_in[19];
    const float* m1w = (const float*)d_in[20];
    const float* m2w = (const float*)d_in[21];
    const float* m3w = (const float*)d_in[22];
    const float* g_[3]  = {(const float*)d_in[23], (const float*)d_in[24], (const float*)d_in[25]};
    const float* be_[3] = {(const float*)d_in[26], (const float*)d_in[27], (const float*)d_in[28]};
    const float* qb  = (const float*)d_in[32];
    const float* kb  = (const float*)d_in[33];
    const float* vb  = (const float*)d_in[34];
    const float* ob  = (const float*)d_in[35];
    const float* m1b = (const float*)d_in[36];
    const float* m2b = (const float*)d_in[37];
    const float* m3b = (const float*)d_in[38];

    const int N = in_sizes[0] / 64; // 8192
    const int E = in_sizes[1] / 2;  // 262144

    float* ws = (float*)d_ws;
    size_t off = 0;
    auto alloc = [&](size_t n) {
        float* p = ws + off;
        off += (n + 255) & ~(size_t)255;
        return p;
    };
    float* hwres = alloc((size_t)N * 512);   // [N][2C] fused w|r output
    float* gout  = alloc((size_t)N * 256);
    unsigned short* sChi = (unsigned short*)alloc((size_t)N * 128); // h0 split
    unsigned short* sClo = (unsigned short*)alloc((size_t)N * 128);
    float* h2   = alloc((size_t)N * 64);
    float* sval = alloc((size_t)N * 4);
    float* dval = alloc((size_t)N * 4);
    float* mu   = alloc(256);
    float* rstd = alloc(256);
    // ---- single-memset region ----
    size_t ms_begin = off;
    int* cnt = (int*)alloc(N);
    double* bnsum = (double*)alloc(3 * 1024);      // 3 layers x 512 doubles
    unsigned* kmaxu = (unsigned*)alloc(64);
    unsigned* svmax = (unsigned*)alloc(16);        // 3 slices: 0,4,8
    size_t ms_end = off;
    // ------------------------------
    int* rowptr = (int*)alloc(N + 256);
    int* fill   = (int*)alloc(N);
    int* srcidx = (int*)alloc(E);
    unsigned short* sAhi = (unsigned short*)alloc((size_t)N * 128);
    unsigned short* sAlo = (unsigned short*)alloc((size_t)N * 128);
    unsigned short* sBhi = (unsigned short*)alloc((size_t)N * 32);
    unsigned short* sBlo = (unsigned short*)alloc((size_t)N * 32);
    // weight split groups (transposed [Ncols][K])
    unsigned short* G0h = (unsigned short*)alloc(512 * 64 / 2);
    unsigned short* G0l = (unsigned short*)alloc(512 * 64 / 2);
    unsigned short* G1h = (unsigned short*)alloc(512 * 256 / 2);
    unsigned short* G1l = (unsigned short*)alloc(512 * 256 / 2);
    unsigned short* G2h = (unsigned short*)alloc(128 * 256 / 2);
    unsigned short* G2l = (unsigned short*)alloc(128 * 256 / 2);
    unsigned short* P0h = (unsigned short*)alloc(64 * 256 / 2);
    unsigned short* P0l = (unsigned short*)alloc(64 * 256 / 2);
    unsigned short* P1h = (unsigned short*)alloc(64 * 256 / 2);
    unsigned short* P1l = (unsigned short*)alloc(64 * 256 / 2);
    unsigned short* Gqh = (unsigned short*)alloc(192 * 64 / 2);
    unsigned short* Gql = (unsigned short*)alloc(192 * 64 / 2);
    unsigned short* Owh = (unsigned short*)alloc(64 * 64 / 2);
    unsigned short* Owl = (unsigned short*)alloc(64 * 64 / 2);
    unsigned short* M1h = (unsigned short*)alloc(64 * 64 / 2);
    unsigned short* M1l = (unsigned short*)alloc(64 * 64 / 2);
    unsigned short* M2h = (unsigned short*)alloc(64 * 64 / 2);
    unsigned short* M2l = (unsigned short*)alloc(64 * 64 / 2);
    unsigned short* M3h = (unsigned short*)alloc(64 * 32 / 2);
    unsigned short* M3l = (unsigned short*)alloc(64 * 32 / 2);
    // aliases
    float* zqkv = hwres;                               // [N][192]
    __hip_bfloat16* pacc = (__hip_bfloat16*)(hwres + (size_t)N * 192);
    float* tA = gout;
    float* tB = gout + (size_t)N * 64;
    float* tC = gout + 2 * (size_t)N * 64;
    const int NCHUNK = 8;
    __hip_bfloat16* Qb = (__hip_bfloat16*)sChi;        // sC dead after JK p0
    __hip_bfloat16* Kb = Qb + (size_t)2 * N * 32;
    __hip_bfloat16* Vf = Kb + (size_t)2 * N * 32;
    float* boundArr = (float*)(Vf + (size_t)2 * N * 32);
    float* pl = h2;                                    // h2 dead after jk_max

    // weights: batch split+transpose (concat via dst offsets)
    {
        WArr wa;
        wa.e[0]  = WEnt{w[0],  G0h,              G0l,              64, 256};
        wa.e[1]  = WEnt{rw[0], G0h + 256 * 64,   G0l + 256 * 64,   64, 256};
        wa.e[2]  = WEnt{w[1],  G1h,              G1l,              256, 256};
        wa.e[3]  = WEnt{rw[1], G1h + 256 * 256,  G1l + 256 * 256,  256, 256};
        wa.e[4]  = WEnt{w[2],  G2h,              G2l,              256, 64};
        wa.e[5]  = WEnt{rw[2], G2h + 64 * 256,   G2l + 64 * 256,   256, 64};
        wa.e[6]  = WEnt{p0,    P0h,              P0l,              256, 64};
        wa.e[7]  = WEnt{p1,    P1h,              P1l,              256, 64};
        wa.e[8]  = WEnt{qw,    Gqh,              Gql,              64, 64};
        wa.e[9]  = WEnt{kw,    Gqh + 64 * 64,    Gql + 64 * 64,    64, 64};
        wa.e[10] = WEnt{vw,    Gqh + 128 * 64,   Gql + 128 * 64,   64, 64};
        wa.e[11] = WEnt{ow,    Owh,              Owl,              64, 64};
        wa.e[12] = WEnt{m1w,   M1h,              M1l,              64, 64};
        wa.e[13] = WEnt{m2w,   M2h,              M2l,              64, 32};
        wa.e[14] = WEnt{m3w,   M3h,              M3l,              32, 10};
        split_weights<<<dim3(256, 15), 256, 0, stream>>>(wa);
    }
    hipMemsetAsync(ws + ms_begin, 0, (ms_end - ms_begin) * 4, stream);
    csr_count<<<(E + 255) / 256, 256, 0, stream>>>(ei, cnt, E);
    csr_scan<<<1, 256, 0, stream>>>(cnt, rowptr, fill, N);
    csr_scatter<<<(E + 255) / 256, 256, 0, stream>>>(ei, fill, srcidx, E);
    split_rows<<<(N * 64 / 4 + 255) / 256, 256, 0, stream>>>(x, sAhi, sAlo, N * 64 / 4);

    auto gemmM = [&](const unsigned short* Ah, const unsigned short* Al,
                     const unsigned short* Bh, const unsigned short* Bl,
                     const float* bias, float* C, unsigned short* Chi,
                     unsigned short* Clo, int M, int Nc, int K, int act) {
        dim3 grid((Nc + 63) / 64, M / 64);
        gemm_mfma<<<grid, 256, 0, stream>>>(Ah, Al, Bh, Bl, bias, C, Chi, Clo,
                                            M, Nc, K, act);
    };

    // ---- 3 GAT layers ----
    const unsigned short* inh[3] = {sAhi, sChi, sAhi};
    const unsigned short* inl[3] = {sAlo, sClo, sAlo};
    unsigned short* outh[3] = {sChi, sAhi, nullptr};
    unsigned short* outl[3] = {sClo, sAlo, nullptr};
    const unsigned short* Gh[3] = {G0h, G1h, G2h};
    const unsigned short* Gl[3] = {G0l, G1l, G2l};
    int Ksz[3] = {64, 256, 256}, Csz[3] = {256, 256, 64}, logC[3] = {8, 8, 6};
    int Hh[3] = {4, 4, 1};

    for (int l = 0; l < 3; ++l) {
        int C = Csz[l], S = 2 * C;
        gemmM(inh[l], inl[l], Gh[l], Gl[l], nullptr, hwres, nullptr, nullptr,
              N, S, Ksz[l], 0);
        if (Hh[l] == 4) {
            sd_kernel<4><<<N * 4 / 256, 256, 0, stream>>>(
                hwres, S, as_[l], ad_[l], sval, dval, svmax + l * 4, N);
            gat_gather<4><<<N / 4, 256, 0, stream>>>(
                rowptr, srcidx, hwres, S, sval, dval, svmax + l * 4, gout, N);
        } else {
            sd_kernel<1><<<N / 256, 256, 0, stream>>>(
                hwres, S, as_[l], ad_[l], sval, dval, svmax + l * 4, N);
            gat_gather<1><<<N / 4, 256, 0, stream>>>(
                rowptr, srcidx, hwres, S, sval, dval, svmax + l * 4, gout, N);
        }
        double* bns = bnsum + l * 512;
        bn_partial<<<N / 32, 256, 0, stream>>>(gout, bns, N, C);
        bn_finalize<<<1, 256, 0, stream>>>(bns, mu, rstd, N, C);
        bn_res_act<<<((size_t)N * C) / 256, 256, 0, stream>>>(
            gout, hwres, S, logC[l], mu, rstd, g_[l], be_[l],
            l == 2 ? h2 : nullptr, outh[l], outl[l], N * C);
    }

    // JumpingKnowledge (h0 split in sC, h1 split in sA)
    gemmM(sChi, sClo, P0h, P0l, nullptr, tA, nullptr, nullptr, N, 64, 256, 0);
    gemmM(sAhi, sAlo, P1h, P1l, nullptr, tB, nullptr, nullptr, N, 64, 256, 0);
    jk_max<<<((size_t)N * 64) / 256, 256, 0, stream>>>(tA, tB, h2, sBhi, sBlo, N * 64);

    // fused qkv GEMM -> zqkv [N][192] (biases folded into preps)
    gemmM(sBhi, sBlo, Gqh, Gql, nullptr, zqkv, nullptr, nullptr, N, 192, 64, 0);

    kmax_kernel<<<32, 256, 0, stream>>>(zqkv, kb, kmaxu, N);
    qk_prep<<<(2 * N + 255) / 256, 256, 0, stream>>>(zqkv, qb, kb, kmaxu, Qb, Kb, boundArr, N);
    v_prep<<<(2 * (N >> 4) * 64 + 255) / 256, 256, 0, stream>>>(zqkv, vb, Vf, N);
    attn_mfma<<<dim3(NCHUNK, (2 * N / 32) / 4), 256, 0, stream>>>(
        Qb, Kb, Vf, boundArr, pl, pacc, N, NCHUNK, N / NCHUNK);
    attn_combine<<<(2 * N * 32 + 255) / 256, 256, 0, stream>>>(
        pl, pacc, sAhi, sAlo, N, NCHUNK);

    // ow + MLP head (split ping-pong sA -> sB -> sA -> sB)
    gemmM(sAhi, sAlo, Owh, Owl, ob, tA, sBhi, sBlo, N, 64, 64, 0);
    gemmM(sBhi, sBlo, M1h, M1l, m1b, tB, sAhi, sAlo, N, 64, 64, 1);
    gemmM(sAhi, sAlo, M2h, M2l, m2b, tC, sBhi, sBlo, N, 32, 64, 1);
    gemmM(sBhi, sBlo, M3h, M3l, m3b, (float*)d_out, nullptr, nullptr, N, 10, 32, 0);
}

// Round 9
// 391.709 us; speedup vs baseline: 2.0030x; 1.0429x over previous
//
#include <hip/hip_runtime.h>
#include <hip/hip_bf16.h>

// NeuronGAT forward. Round 8:
//  - attn_mfma: v_cvt_pk_bf16_f32 packing (1 instr vs ~8 manual ops) and
//    exp2-domain softmax (log2e folded into Q/bound at prep) -> VALU cut ~2x.
//  - gat_gather H=4: float4-per-lane (head = lane>>4 is lane-constant):
//    1 dwordx4 + 1 exp per edge instead of 4 strided loads + 4 exp.
//    sval/dval pre-scaled by log2e in sd_kernel (leaky is pos-homogeneous).
//  - rest unchanged from r7 (split-bf16 MFMA GEMMs, single-pass gather, fusions).

#define NEG 0.2f
#define LOG2E 1.4426950408889634f

__device__ __forceinline__ float leaky(float v) { return v > 0.f ? v : NEG * v; }

__device__ __forceinline__ unsigned bf16u(float x) {
    unsigned u = __float_as_uint(x);
    u += 0x7FFFu + ((u >> 16) & 1u);
    return u >> 16;
}
__device__ __forceinline__ unsigned fmap(float f) {
    unsigned u = __float_as_uint(f);
    return (u & 0x80000000u) ? ~u : (u | 0x80000000u);
}
__device__ __forceinline__ float funmap(unsigned u) {
    unsigned b = (u & 0x80000000u) ? (u & 0x7FFFFFFFu) : ~u;
    return __uint_as_float(b);
}
__device__ __forceinline__ float fexp2(float x) {
#if __has_builtin(__builtin_amdgcn_exp2f)
    return __builtin_amdgcn_exp2f(x);
#else
    return exp2f(x);
#endif
}
// packed fp32x2 -> bf16x2 (single HW instr; no builtin on gfx950)
__device__ __forceinline__ unsigned cvtpk(float lo, float hi) {
    unsigned r;
    asm("v_cvt_pk_bf16_f32 %0, %1, %2" : "=v"(r) : "v"(lo), "v"(hi));
    return r;
}

typedef __attribute__((ext_vector_type(8))) short bf16x8;
typedef __attribute__((ext_vector_type(16))) float f32x16;
typedef __attribute__((ext_vector_type(4))) unsigned uint4v;

__device__ __forceinline__ void split1(float v, unsigned& hb, unsigned& lb) {
    hb = bf16u(v);
    float hf = __uint_as_float(hb << 16);
    lb = bf16u(v - hf);
}

__global__ void split_rows(const float* __restrict__ in,
                           unsigned short* __restrict__ hi,
                           unsigned short* __restrict__ lo, int total4)
{
    int i = blockIdx.x * 256 + threadIdx.x;
    if (i >= total4) return;
    float4 v = ((const float4*)in)[i];
    float vv[4] = {v.x, v.y, v.z, v.w};
    ushort4 h, l;
#pragma unroll
    for (int j = 0; j < 4; ++j) {
        unsigned hb, lb;
        split1(vv[j], hb, lb);
        (&h.x)[j] = (unsigned short)hb;
        (&l.x)[j] = (unsigned short)lb;
    }
    ((ushort4*)hi)[i] = h;
    ((ushort4*)lo)[i] = l;
}

struct WEnt { const float* src; unsigned short* hi; unsigned short* lo; int K; int N; };
struct WArr { WEnt e[15]; };

__global__ void split_weights(WArr a)
{
    WEnt w = a.e[blockIdx.y];
    int id = blockIdx.x * 256 + threadIdx.x;
    if (id >= w.K * w.N) return;
    int k = id / w.N, n = id - k * w.N;
    unsigned hb, lb;
    split1(w.src[id], hb, lb);
    w.hi[(size_t)n * w.K + k] = (unsigned short)hb;
    w.lo[(size_t)n * w.K + k] = (unsigned short)lb;
}

// ------------------------------------------------- MFMA split-bf16 GEMM (r6)
__global__ __launch_bounds__(256) void gemm_mfma(
    const unsigned short* __restrict__ Ahi, const unsigned short* __restrict__ Alo,
    const unsigned short* __restrict__ Bhi, const unsigned short* __restrict__ Blo,
    const float* __restrict__ bias, float* __restrict__ C,
    unsigned short* __restrict__ Chi, unsigned short* __restrict__ Clo,
    int M, int N, int K, int act)
{
    const int lane = threadIdx.x & 63, wid = threadIdx.x >> 6;
    const int hb4 = lane >> 5, lq = lane & 31;
    const int row0 = blockIdx.y * 64 + (wid >> 1) * 32;
    const int col0 = blockIdx.x * 64 + (wid & 1) * 32;
    const size_t abase = (size_t)(row0 + lq) * K + hb4 * 8;
    const size_t bbase = (size_t)(col0 + lq) * K + hb4 * 8;
    f32x16 acc0, acc1;
#pragma unroll
    for (int r = 0; r < 16; ++r) { acc0[r] = 0.f; acc1[r] = 0.f; }
    for (int k0 = 0; k0 < K; k0 += 16) {
        bf16x8 a_h = *(const bf16x8*)(Ahi + abase + k0);
        bf16x8 a_l = *(const bf16x8*)(Alo + abase + k0);
        bf16x8 b_h = *(const bf16x8*)(Bhi + bbase + k0);
        bf16x8 b_l = *(const bf16x8*)(Blo + bbase + k0);
        acc0 = __builtin_amdgcn_mfma_f32_32x32x16_bf16(a_h, b_h, acc0, 0, 0, 0);
        acc1 = __builtin_amdgcn_mfma_f32_32x32x16_bf16(a_l, b_h, acc1, 0, 0, 0);
        acc1 = __builtin_amdgcn_mfma_f32_32x32x16_bf16(a_h, b_l, acc1, 0, 0, 0);
    }
    int col = col0 + lq;
    if (col >= N) return;
    float bs = bias ? bias[col] : 0.f;
#pragma unroll
    for (int r = 0; r < 16; ++r) {
        int row = row0 + (r & 3) + 8 * (r >> 2) + 4 * hb4;
        float v = acc0[r] + acc1[r] + bs;
        if (act) v = leaky(v);
        C[(size_t)row * N + col] = v;
        if (Chi) {
            unsigned hh, ll;
            split1(v, hh, ll);
            Chi[(size_t)row * N + col] = (unsigned short)hh;
            Clo[(size_t)row * N + col] = (unsigned short)ll;
        }
    }
}

// ---------------------------------- GAT scores (x log2e) + global head max
template <int H>
__global__ __launch_bounds__(256) void sd_kernel(
    const float* __restrict__ hwres, int S,
    const float* __restrict__ a_s, const float* __restrict__ a_d,
    float* __restrict__ sval, float* __restrict__ dval,
    unsigned* __restrict__ svmax, int Nn)
{
    int i = blockIdx.x * 256 + threadIdx.x;
    int n = i / H, h = i & (H - 1);
    const float4* row = (const float4*)(hwres + (size_t)n * S + h * 64);
    const float4* as4 = (const float4*)(a_s + h * 64);
    const float4* ad4 = (const float4*)(a_d + h * 64);
    float s = 0.f, d = 0.f;
#pragma unroll
    for (int c = 0; c < 16; ++c) {
        float4 x = row[c], a = as4[c], b = ad4[c];
        s += x.x * a.x + x.y * a.y + x.z * a.z + x.w * a.w;
        d += x.x * b.x + x.y * b.y + x.z * b.z + x.w * b.w;
    }
    s *= LOG2E;            // exp2 domain (leaky is positively homogeneous)
    d *= LOG2E;
    sval[i] = s;
    dval[i] = d;
    float m = s;
#pragma unroll
    for (int off = H; off < 64; off <<= 1) m = fmaxf(m, __shfl_xor(m, off));
    if ((threadIdx.x & 63) < H) atomicMax(&svmax[h], fmap(m));
}

// ------------------------------------------------- CSR build (by dst)
__global__ void csr_count(const int* __restrict__ ei, int* __restrict__ cnt, int E) {
    int i = blockIdx.x * 256 + threadIdx.x;
    if (i < E) atomicAdd(&cnt[ei[E + i]], 1);
}

__global__ __launch_bounds__(256) void csr_scan(const int* __restrict__ cnt,
                                                int* __restrict__ rowptr,
                                                int* __restrict__ fill, int Nn)
{
    __shared__ int part[256];
    int t = threadIdx.x;
    int loc[32];
    int s = 0;
#pragma unroll
    for (int j = 0; j < 32; ++j) { loc[j] = s; s += cnt[t * 32 + j]; }
    part[t] = s;
    __syncthreads();
    for (int d = 1; d < 256; d <<= 1) {
        int v = (t >= d) ? part[t - d] : 0;
        __syncthreads();
        part[t] += v;
        __syncthreads();
    }
    int off = (t > 0) ? part[t - 1] : 0;
#pragma unroll
    for (int j = 0; j < 32; ++j) {
        int v = off + loc[j];
        rowptr[t * 32 + j] = v;
        fill[t * 32 + j] = v;
    }
    if (t == 255) rowptr[Nn] = part[255];
}

__global__ void csr_scatter(const int* __restrict__ ei, int* __restrict__ fill,
                            int* __restrict__ srcidx, int E) {
    int i = blockIdx.x * 256 + threadIdx.x;
    if (i < E) {
        int d = ei[E + i];
        int p = atomicAdd(&fill[d], 1);
        srcidx[p] = ei[i];
    }
}

// ------------------- single-pass GAT gather, H=4: float4-per-lane
// channel c = 4*lane+j  =>  head = lane>>4 (lane-constant). One dwordx4 +
// one exp2 per edge. Fixed bound B (exp2 domain) => no cross-lane softmax.
__global__ __launch_bounds__(256) void gat_gather4(
    const int* __restrict__ rowptr, const int* __restrict__ srcidx,
    const float* __restrict__ hwres, int S,
    const float* __restrict__ sval, const float* __restrict__ dval,
    const unsigned* __restrict__ svmax, float* __restrict__ gout, int Nn)
{
    const int node = blockIdx.x * 4 + (threadIdx.x >> 6);
    const int lane = threadIdx.x & 63;
    const int hd = lane >> 4;
    const int cb = lane * 4;
    const int beg = rowptr[node], end = rowptr[node + 1];
    const float dv = dval[node * 4 + hd];
    const float B = leaky(funmap(svmax[hd]) + dv);
    float p = fexp2(leaky(sval[node * 4 + hd] + dv) - B);   // self-loop
    float l = p;
    float4 hv = *(const float4*)(hwres + (size_t)node * S + cb);
    float a0 = p * hv.x, a1 = p * hv.y, a2 = p * hv.z, a3 = p * hv.w;
    int i = beg;
    for (; i + 2 <= end; i += 2) {
        int s0 = srcidx[i], s1 = srcidx[i + 1];
        float p0 = fexp2(leaky(sval[s0 * 4 + hd] + dv) - B);
        float p1 = fexp2(leaky(sval[s1 * 4 + hd] + dv) - B);
        float4 r0 = *(const float4*)(hwres + (size_t)s0 * S + cb);
        float4 r1 = *(const float4*)(hwres + (size_t)s1 * S + cb);
        l += p0 + p1;
        a0 += p0 * r0.x + p1 * r1.x;
        a1 += p0 * r0.y + p1 * r1.y;
        a2 += p0 * r0.z + p1 * r1.z;
        a3 += p0 * r0.w + p1 * r1.w;
    }
    if (i < end) {
        int s0 = srcidx[i];
        float p0 = fexp2(leaky(sval[s0 * 4 + hd] + dv) - B);
        float4 r0 = *(const float4*)(hwres + (size_t)s0 * S + cb);
        l += p0;
        a0 += p0 * r0.x; a1 += p0 * r0.y; a2 += p0 * r0.z; a3 += p0 * r0.w;
    }
    float inv = 1.f / l;
    *(float4*)(gout + (size_t)node * 256 + cb) =
        make_float4(a0 * inv, a1 * inv, a2 * inv, a3 * inv);
}

// H=1 scalar path (layer 3; light traffic)
__global__ __launch_bounds__(256) void gat_gather1(
    const int* __restrict__ rowptr, const int* __restrict__ srcidx,
    const float* __restrict__ hwres, int S,
    const float* __restrict__ sval, const float* __restrict__ dval,
    const unsigned* __restrict__ svmax, float* __restrict__ gout, int Nn)
{
    const int node = blockIdx.x * 4 + (threadIdx.x >> 6);
    const int lane = threadIdx.x & 63;
    const int beg = rowptr[node], end = rowptr[node + 1];
    const float dv = dval[node];
    const float B = leaky(funmap(svmax[0]) + dv);
    float p = fexp2(leaky(sval[node] + dv) - B);
    float l = p;
    float acc = p * hwres[(size_t)node * S + lane];
    int i = beg;
    for (; i + 2 <= end; i += 2) {
        int s0 = srcidx[i], s1 = srcidx[i + 1];
        float p0 = fexp2(leaky(sval[s0] + dv) - B);
        float p1 = fexp2(leaky(sval[s1] + dv) - B);
        l += p0 + p1;
        acc += p0 * hwres[(size_t)s0 * S + lane] + p1 * hwres[(size_t)s1 * S + lane];
    }
    if (i < end) {
        int s0 = srcidx[i];
        float p0 = fexp2(leaky(sval[s0] + dv) - B);
        l += p0;
        acc += p0 * hwres[(size_t)s0 * S + lane];
    }
    gout[(size_t)node * 64 + lane] = acc / l;
}

// ------------------------------------------------- BatchNorm (batch stats)
__global__ void bn_partial(const float* __restrict__ gout, double* __restrict__ sums,
                           int Nn, int C)
{
    int t = threadIdx.x;
    int c = t % C, sub = t / C, nsub = blockDim.x / C;
    int rbase = blockIdx.x * 32;
    double s = 0.0, sq = 0.0;
    for (int r = rbase + sub; r < rbase + 32; r += nsub) {
        float x = gout[(size_t)r * C + c];
        s += x;
        sq += (double)x * x;
    }
    atomicAdd(&sums[c], s);
    atomicAdd(&sums[C + c], sq);
}

__global__ void bn_finalize(const double* __restrict__ sums, float* __restrict__ mu,
                            float* __restrict__ rstd, int Nn, int C)
{
    int c = threadIdx.x;
    if (c >= C) return;
    double m = sums[c] / Nn;
    double v = sums[C + c] / Nn - m * m;
    mu[c] = (float)m;
    rstd[c] = (float)(1.0 / sqrt(v + 1e-5));
}

__global__ void bn_res_act(const float* __restrict__ gout,
                           const float* __restrict__ hwres, int S, int logC,
                           const float* __restrict__ mu, const float* __restrict__ rstd,
                           const float* __restrict__ g, const float* __restrict__ be,
                           float* __restrict__ outp,
                           unsigned short* __restrict__ shi,
                           unsigned short* __restrict__ slo, int total)
{
    int i = blockIdx.x * blockDim.x + threadIdx.x;
    if (i >= total) return;
    int C = 1 << logC;
    int c = i & (C - 1), row = i >> logC;
    float v = (gout[i] - mu[c]) * rstd[c] * g[c] + be[c]
              + hwres[(size_t)row * S + C + c];
    v = leaky(v);
    if (outp) outp[i] = v;
    if (shi) {
        unsigned hb, lb;
        split1(v, hb, lb);
        shi[i] = (unsigned short)hb;
        slo[i] = (unsigned short)lb;
    }
}

__global__ void jk_max(const float* __restrict__ a, const float* __restrict__ b,
                       const float* __restrict__ c,
                       unsigned short* __restrict__ shi,
                       unsigned short* __restrict__ slo, int total)
{
    int i = blockIdx.x * blockDim.x + threadIdx.x;
    if (i >= total) return;
    float v = fmaxf(fmaxf(a[i], b[i]), c[i]);
    unsigned hb, lb;
    split1(v, hb, lb);
    shi[i] = (unsigned short)hb;
    slo[i] = (unsigned short)lb;
}

// ------------------------------------------------- per-dim |k| max (biased k)
__global__ void kmax_kernel(const float* __restrict__ zqkv,
                            const float* __restrict__ kb,
                            unsigned* __restrict__ kmax, int N)
{
    const int c = threadIdx.x & 63, g = threadIdx.x >> 6;
    const int rows = N / (gridDim.x * 4);
    const int r0 = (blockIdx.x * 4 + g) * rows;
    float bc = kb[c];
    float m = 0.f;
    for (int r = r0; r < r0 + rows; ++r)
        m = fmaxf(m, fabsf(zqkv[(size_t)r * 192 + 64 + c] + bc));
    atomicMax(&kmax[c], __float_as_uint(m));
}

// -------------------------- attn prep: Q scaled by scale*log2e (exp2 domain)
__global__ void qk_prep(const float* __restrict__ zqkv,
                        const float* __restrict__ qb, const float* __restrict__ kb,
                        const unsigned* __restrict__ kmaxu,
                        __hip_bfloat16* __restrict__ Qb, __hip_bfloat16* __restrict__ Kb,
                        float* __restrict__ bound, int N)
{
    int idx = blockIdx.x * 256 + threadIdx.x;
    if (idx >= 2 * N) return;
    int h = idx / N, row = idx - h * N;
    const float scale = 0.17677669529663687f * LOG2E;
    const float* qp = zqkv + (size_t)row * 192 + h * 32;
    const float* kp = zqkv + (size_t)row * 192 + 64 + h * 32;
    float b = 0.f;
    unsigned qo[16], ko[16];
#pragma unroll
    for (int i = 0; i < 16; ++i) {
        float q0 = (qp[2 * i] + qb[h * 32 + 2 * i]) * scale;
        float q1 = (qp[2 * i + 1] + qb[h * 32 + 2 * i + 1]) * scale;
        float k0 = kp[2 * i] + kb[h * 32 + 2 * i];
        float k1 = kp[2 * i + 1] + kb[h * 32 + 2 * i + 1];
        b += fabsf(q0) * __uint_as_float(kmaxu[h * 32 + 2 * i]);
        b += fabsf(q1) * __uint_as_float(kmaxu[h * 32 + 2 * i + 1]);
        qo[i] = bf16u(q0) | (bf16u(q1) << 16);
        ko[i] = bf16u(k0) | (bf16u(k1) << 16);
    }
    uint4* qd = (uint4*)(Qb + (size_t)idx * 32);
    uint4* kd = (uint4*)(Kb + (size_t)idx * 32);
#pragma unroll
    for (int i = 0; i < 4; ++i) {
        qd[i] = make_uint4(qo[4 * i], qo[4 * i + 1], qo[4 * i + 2], qo[4 * i + 3]);
        kd[i] = make_uint4(ko[4 * i], ko[4 * i + 1], ko[4 * i + 2], ko[4 * i + 3]);
    }
    bound[idx] = b;
}

__global__ void v_prep(const float* __restrict__ zqkv, const float* __restrict__ vb,
                       __hip_bfloat16* __restrict__ Vf, int N)
{
    int idx = blockIdx.x * 256 + threadIdx.x;
    int total = 2 * (N >> 4) * 64;
    if (idx >= total) return;
    int lane = idx & 63;
    int g = (idx >> 6) % (N >> 4);
    int h = (idx >> 6) / (N >> 4);
    int kb_ = g * 16 + (lane >> 5) * 8;
    int d = (lane & 31) + h * 32;
    float bd = vb[d];
    unsigned o[4];
#pragma unroll
    for (int i = 0; i < 4; ++i) {
        unsigned u0 = bf16u(zqkv[(size_t)(kb_ + 2 * i) * 192 + 128 + d] + bd);
        unsigned u1 = bf16u(zqkv[(size_t)(kb_ + 2 * i + 1) * 192 + 128 + d] + bd);
        o[i] = u0 | (u1 << 16);
    }
    *(uint4*)(Vf + (size_t)idx * 8) = make_uint4(o[0], o[1], o[2], o[3]);
}

// ------------------------------------------------- MFMA self-attention
__global__ __launch_bounds__(256) void attn_mfma(
    const __hip_bfloat16* __restrict__ Qb, const __hip_bfloat16* __restrict__ Kb,
    const __hip_bfloat16* __restrict__ Vf, const float* __restrict__ bound,
    float* __restrict__ pl, __hip_bfloat16* __restrict__ pacc,
    int N, int nchunk, int chunksz)
{
    const int lane = threadIdx.x & 63;
    const int wid = threadIdx.x >> 6;
    const int hi = lane >> 5, lq = lane & 31;
    const int chunk = blockIdx.x;
    const int qtile = blockIdx.y * 4 + wid;
    const int head = qtile / (N >> 5);
    const int q0 = (qtile % (N >> 5)) * 32;
    const int kbase = chunk * chunksz;

    const size_t qrow = (size_t)head * N + q0 + lq;
    const bf16x8 qf0 = *(const bf16x8*)(Qb + qrow * 32 + hi * 8);
    const bf16x8 qf1 = *(const bf16x8*)(Qb + qrow * 32 + hi * 8 + 16);
    const float bnd = bound[qrow];

    f32x16 oacc;
#pragma unroll
    for (int r = 0; r < 16; ++r) oacc[r] = 0.f;
    float lsum = 0.f;

    for (int kt = kbase; kt < kbase + chunksz; kt += 32) {
        const size_t krow = (size_t)head * N + kt + lq;
        const bf16x8 kf0 = *(const bf16x8*)(Kb + krow * 32 + hi * 8);
        const bf16x8 kf1 = *(const bf16x8*)(Kb + krow * 32 + hi * 8 + 16);
        f32x16 s;
#pragma unroll
        for (int r = 0; r < 16; ++r) s[r] = 0.f;
        s = __builtin_amdgcn_mfma_f32_32x32x16_bf16(kf0, qf0, s, 0, 0, 0);
        s = __builtin_amdgcn_mfma_f32_32x32x16_bf16(kf1, qf1, s, 0, 0, 0);
        const __hip_bfloat16* vfb =
            Vf + (((size_t)head * (N >> 4) + (kt >> 4)) * 64 + lane) * 8;
        const bf16x8 vf0 = *(const bf16x8*)vfb;
        const bf16x8 vf1 = *(const bf16x8*)(vfb + 64 * 8);

        float p[16];
#pragma unroll
        for (int r = 0; r < 16; ++r) p[r] = fexp2(s[r] - bnd);  // exp2 domain
        float ls = 0.f;
#pragma unroll
        for (int r = 0; r < 16; ++r) ls += p[r];
        lsum += ls;

        unsigned wpk[8];
#pragma unroll
        for (int i = 0; i < 8; ++i) wpk[i] = cvtpk(p[2 * i], p[2 * i + 1]);
        unsigned wsx[8];
#pragma unroll
        for (int i = 0; i < 8; ++i) wsx[i] = (unsigned)__shfl_xor((int)wpk[i], 32);
        uint4v b1, b2;
        b1[0] = hi ? wsx[2] : wpk[0];
        b1[1] = hi ? wsx[3] : wpk[1];
        b1[2] = hi ? wpk[2] : wsx[0];
        b1[3] = hi ? wpk[3] : wsx[1];
        b2[0] = hi ? wsx[6] : wpk[4];
        b2[1] = hi ? wsx[7] : wpk[5];
        b2[2] = hi ? wpk[6] : wsx[4];
        b2[3] = hi ? wpk[7] : wsx[5];
        oacc = __builtin_amdgcn_mfma_f32_32x32x16_bf16(
            vf0, __builtin_bit_cast(bf16x8, b1), oacc, 0, 0, 0);
        oacc = __builtin_amdgcn_mfma_f32_32x32x16_bf16(
            vf1, __builtin_bit_cast(bf16x8, b2), oacc, 0, 0, 0);
    }
    lsum += __shfl_xor(lsum, 32);
    const size_t hr = (size_t)head * N + q0 + lq;
    if (hi == 0) pl[hr * nchunk + chunk] = lsum;
    __hip_bfloat16* pb = pacc + (hr * nchunk + chunk) * 32;
#pragma unroll
    for (int rg = 0; rg < 4; ++rg) {
        unsigned lo = cvtpk(oacc[rg * 4 + 0], oacc[rg * 4 + 1]);
        unsigned hw2 = cvtpk(oacc[rg * 4 + 2], oacc[rg * 4 + 3]);
        *(uint2*)(pb + rg * 8 + hi * 4) = make_uint2(lo, hw2);
    }
}

__global__ void attn_combine(const float* __restrict__ pl,
                             const __hip_bfloat16* __restrict__ pacc,
                             unsigned short* __restrict__ shi,
                             unsigned short* __restrict__ slo, int N, int nchunk)
{
    int i = blockIdx.x * blockDim.x + threadIdx.x;
    if (i >= 2 * N * 32) return;
    int hr = i >> 5, cc = i & 31;
    float l = 0.f, a = 0.f;
    for (int c = 0; c < nchunk; ++c) {
        l += pl[(size_t)hr * nchunk + c];
        a += __bfloat162float(pacc[((size_t)hr * nchunk + c) * 32 + cc]);
    }
    int head = hr / N, row = hr - head * N;
    float v = a / l;
    size_t oi = (size_t)row * 64 + head * 32 + cc;
    unsigned hb, lb;
    split1(v, hb, lb);
    shi[oi] = (unsigned short)hb;
    slo[oi] = (unsigned short)lb;
}

// ----------------------------------------------------------------- host
extern "C" void kernel_launch(void* const* d_in, const int* in_sizes, int n_in,
                              void* d_out, int out_size, void* d_ws, size_t ws_size,
                              hipStream_t stream)
{
    const float* x = (const float*)d_in[0];
    const int* ei = (const int*)d_in[1];
    const float* w[3]   = {(const float*)d_in[2], (const float*)d_in[6],  (const float*)d_in[10]};
    const float* as_[3] = {(const float*)d_in[3], (const float*)d_in[7],  (const float*)d_in[11]};
    const float* ad_[3] = {(const float*)d_in[4], (const float*)d_in[8],  (const float*)d_in[12]};
    const float* rw[3]  = {(const float*)d_in[5], (const float*)d_in[9],  (const float*)d_in[13]};
    const float* p0 = (const float*)d_in[14];
    const float* p1 = (const float*)d_in[15];
    const float* qw = (const float*)d_in[16];
    const float* kw = (const float*)d_in[17];
    const float* vw = (const float*)d_in[18];
    const float* ow = (const float*)d_in[19];
    const float* m1w = (const float*)d_in[20];
    const float* m2w = (const float*)d_in[21];
    const float* m3w = (const float*)d_in[22];
    const float* g_[3]  = {(const float*)d_in[23], (const float*)d_in[24], (const float*)d_in[25]};
    const float* be_[3] = {(const float*)d_in[26], (const float*)d_in[27], (const float*)d_in[28]};
    const float* qb  = (const float*)d_in[32];
    const float* kb  = (const float*)d_in[33];
    const float* vb  = (const float*)d_in[34];
    const float* ob  = (const float*)d_in[35];
    const float* m1b = (const float*)d_in[36];
    const float* m2b = (const float*)d_in[37];
    const float* m3b = (const float*)d_in[38];

    const int N = in_sizes[0] / 64; // 8192
    const int E = in_sizes[1] / 2;  // 262144

    float* ws = (float*)d_ws;
    size_t off = 0;
    auto alloc = [&](size_t n) {
        float* p = ws + off;
        off += (n + 255) & ~(size_t)255;
        return p;
    };
    float* hwres = alloc((size_t)N * 512);
    float* gout  = alloc((size_t)N * 256);
    unsigned short* sChi = (unsigned short*)alloc((size_t)N * 128);
    unsigned short* sClo = (unsigned short*)alloc((size_t)N * 128);
    float* h2   = alloc((size_t)N * 64);
    float* sval = alloc((size_t)N * 4);
    float* dval = alloc((size_t)N * 4);
    float* mu   = alloc(256);
    float* rstd = alloc(256);
    size_t ms_begin = off;
    int* cnt = (int*)alloc(N);
    double* bnsum = (double*)alloc(3 * 1024);
    unsigned* kmaxu = (unsigned*)alloc(64);
    unsigned* svmax = (unsigned*)alloc(16);
    size_t ms_end = off;
    int* rowptr = (int*)alloc(N + 256);
    int* fill   = (int*)alloc(N);
    int* srcidx = (int*)alloc(E);
    unsigned short* sAhi = (unsigned short*)alloc((size_t)N * 128);
    unsigned short* sAlo = (unsigned short*)alloc((size_t)N * 128);
    unsigned short* sBhi = (unsigned short*)alloc((size_t)N * 32);
    unsigned short* sBlo = (unsigned short*)alloc((size_t)N * 32);
    unsigned short* G0h = (unsigned short*)alloc(512 * 64 / 2);
    unsigned short* G0l = (unsigned short*)alloc(512 * 64 / 2);
    unsigned short* G1h = (unsigned short*)alloc(512 * 256 / 2);
    unsigned short* G1l = (unsigned short*)alloc(512 * 256 / 2);
    unsigned short* G2h = (unsigned short*)alloc(128 * 256 / 2);
    unsigned short* G2l = (unsigned short*)alloc(128 * 256 / 2);
    unsigned short* P0h = (unsigned short*)alloc(64 * 256 / 2);
    unsigned short* P0l = (unsigned short*)alloc(64 * 256 / 2);
    unsigned short* P1h = (unsigned short*)alloc(64 * 256 / 2);
    unsigned short* P1l = (unsigned short*)alloc(64 * 256 / 2);
    unsigned short* Gqh = (unsigned short*)alloc(192 * 64 / 2);
    unsigned short* Gql = (unsigned short*)alloc(192 * 64 / 2);
    unsigned short* Owh = (unsigned short*)alloc(64 * 64 / 2);
    unsigned short* Owl = (unsigned short*)alloc(64 * 64 / 2);
    unsigned short* M1h = (unsigned short*)alloc(64 * 64 / 2);
    unsigned short* M1l = (unsigned short*)alloc(64 * 64 / 2);
    unsigned short* M2h = (unsigned short*)alloc(64 * 64 / 2);
    unsigned short* M2l = (unsigned short*)alloc(64 * 64 / 2);
    unsigned short* M3h = (unsigned short*)alloc(64 * 32 / 2);
    unsigned short* M3l = (unsigned short*)alloc(64 * 32 / 2);
    float* zqkv = hwres;
    __hip_bfloat16* pacc = (__hip_bfloat16*)(hwres + (size_t)N * 192);
    float* tA = gout;
    float* tB = gout + (size_t)N * 64;
    float* tC = gout + 2 * (size_t)N * 64;
    const int NCHUNK = 8;
    __hip_bfloat16* Qb = (__hip_bfloat16*)sChi;
    __hip_bfloat16* Kb = Qb + (size_t)2 * N * 32;
    __hip_bfloat16* Vf = Kb + (size_t)2 * N * 32;
    float* boundArr = (float*)(Vf + (size_t)2 * N * 32);
    float* pl = h2;

    {
        WArr wa;
        wa.e[0]  = WEnt{w[0],  G0h,              G0l,              64, 256};
        wa.e[1]  = WEnt{rw[0], G0h + 256 * 64,   G0l + 256 * 64,   64, 256};
        wa.e[2]  = WEnt{w[1],  G1h,              G1l,              256, 256};
        wa.e[3]  = WEnt{rw[1], G1h + 256 * 256,  G1l + 256 * 256,  256, 256};
        wa.e[4]  = WEnt{w[2],  G2h,              G2l,              256, 64};
        wa.e[5]  = WEnt{rw[2], G2h + 64 * 256,   G2l + 64 * 256,   256, 64};
        wa.e[6]  = WEnt{p0,    P0h,              P0l,              256, 64};
        wa.e[7]  = WEnt{p1,    P1h,              P1l,              256, 64};
        wa.e[8]  = WEnt{qw,    Gqh,              Gql,              64, 64};
        wa.e[9]  = WEnt{kw,    Gqh + 64 * 64,    Gql + 64 * 64,    64, 64};
        wa.e[10] = WEnt{vw,    Gqh + 128 * 64,   Gql + 128 * 64,   64, 64};
        wa.e[11] = WEnt{ow,    Owh,              Owl,              64, 64};
        wa.e[12] = WEnt{m1w,   M1h,              M1l,              64, 64};
        wa.e[13] = WEnt{m2w,   M2h,              M2l,              64, 32};
        wa.e[14] = WEnt{m3w,   M3h,              M3l,              32, 10};
        split_weights<<<dim3(256, 15), 256, 0, stream>>>(wa);
    }
    hipMemsetAsync(ws + ms_begin, 0, (ms_end - ms_begin) * 4, stream);
    csr_count<<<(E + 255) / 256, 256, 0, stream>>>(ei, cnt, E);
    csr_scan<<<1, 256, 0, stream>>>(cnt, rowptr, fill, N);
    csr_scatter<<<(E + 255) / 256, 256, 0, stream>>>(ei, fill, srcidx, E);
    split_rows<<<(N * 64 / 4 + 255) / 256, 256, 0, stream>>>(x, sAhi, sAlo, N * 64 / 4);

    auto gemmM = [&](const unsigned short* Ah, const unsigned short* Al,
                     const unsigned short* Bh, const unsigned short* Bl,
                     const float* bias, float* C, unsigned short* Chi,
                     unsigned short* Clo, int M, int Nc, int K, int act) {
        dim3 grid((Nc + 63) / 64, M / 64);
        gemm_mfma<<<grid, 256, 0, stream>>>(Ah, Al, Bh, Bl, bias, C, Chi, Clo,
                                            M, Nc, K, act);
    };

    const unsigned short* inh[3] = {sAhi, sChi, sAhi};
    const unsigned short* inl[3] = {sAlo, sClo, sAlo};
    unsigned short* outh[3] = {sChi, sAhi, nullptr};
    unsigned short* outl[3] = {sClo, sAlo, nullptr};
    const unsigned short* Gh[3] = {G0h, G1h, G2h};
    const unsigned short* Gl[3] = {G0l, G1l, G2l};
    int Ksz[3] = {64, 256, 256}, Csz[3] = {256, 256, 64}, logC[3] = {8, 8, 6};
    int Hh[3] = {4, 4, 1};

    for (int l = 0; l < 3; ++l) {
        int C = Csz[l], S = 2 * C;
        gemmM(inh[l], inl[l], Gh[l], Gl[l], nullptr, hwres, nullptr, nullptr,
              N, S, Ksz[l], 0);
        if (Hh[l] == 4) {
            sd_kernel<4><<<N * 4 / 256, 256, 0, stream>>>(
                hwres, S, as_[l], ad_[l], sval, dval, svmax + l * 4, N);
            gat_gather4<<<N / 4, 256, 0, stream>>>(
                rowptr, srcidx, hwres, S, sval, dval, svmax + l * 4, gout, N);
        } else {
            sd_kernel<1><<<N / 256, 256, 0, stream>>>(
                hwres, S, as_[l], ad_[l], sval, dval, svmax + l * 4, N);
            gat_gather1<<<N / 4, 256, 0, stream>>>(
                rowptr, srcidx, hwres, S, sval, dval, svmax + l * 4, gout, N);
        }
        double* bns = bnsum + l * 512;
        bn_partial<<<N / 32, 256, 0, stream>>>(gout, bns, N, C);
        bn_finalize<<<1, 256, 0, stream>>>(bns, mu, rstd, N, C);
        bn_res_act<<<((size_t)N * C) / 256, 256, 0, stream>>>(
            gout, hwres, S, logC[l], mu, rstd, g_[l], be_[l],
            l == 2 ? h2 : nullptr, outh[l], outl[l], N * C);
    }

    gemmM(sChi, sClo, P0h, P0l, nullptr, tA, nullptr, nullptr, N, 64, 256, 0);
    gemmM(sAhi, sAlo, P1h, P1l, nullptr, tB, nullptr, nullptr, N, 64, 256, 0);
    jk_max<<<((size_t)N * 64) / 256, 256, 0, stream>>>(tA, tB, h2, sBhi, sBlo, N * 64);

    gemmM(sBhi, sBlo, Gqh, Gql, nullptr, zqkv, nullptr, nullptr, N, 192, 64, 0);

    kmax_kernel<<<32, 256, 0, stream>>>(zqkv, kb, kmaxu, N);
    qk_prep<<<(2 * N + 255) / 256, 256, 0, stream>>>(zqkv, qb, kb, kmaxu, Qb, Kb, boundArr, N);
    v_prep<<<(2 * (N >> 4) * 64 + 255) / 256, 256, 0, stream>>>(zqkv, vb, Vf, N);
    attn_mfma<<<dim3(NCHUNK, (2 * N / 32) / 4), 256, 0, stream>>>(
        Qb, Kb, Vf, boundArr, pl, pacc, N, NCHUNK, N / NCHUNK);
    attn_combine<<<(2 * N * 32 + 255) / 256, 256, 0, stream>>>(
        pl, pacc, sAhi, sAlo, N, NCHUNK);

    gemmM(sAhi, sAlo, Owh, Owl, ob, tA, sBhi, sBlo, N, 64, 64, 0);
    gemmM(sBhi, sBlo, M1h, M1l, m1b, tB, sAhi, sAlo, N, 64, 64, 1);
    gemmM(sAhi, sAlo, M2h, M2l, m2b, tC, sBhi, sBlo, N, 32, 64, 1);
    gemmM(sBhi, sBlo, M3h, M3l, m3b, (float*)d_out, nullptr, nullptr, N, 10, 32, 0);
}